// Round 1
// baseline (2340.270 us; speedup 1.0000x reference)
//
#include <hip/hip_runtime.h>
#include <hip/hip_bf16.h>
#include <math.h>

// Problem constants
#define DM    512
#define DI    1024
#define DSN   16
#define DCONV 4
#define DTR   32
#define DFFN  2048
#define BB    8
#define SS    512
#define TTM   1024
#define LCAT  1536

#define ACT_NONE     0
#define ACT_RELU     1
#define ACT_SOFTPLUS 2

__device__ __forceinline__ int map_row(int m, int mb, int bs, int ro) {
    int q = m / mb;
    return q * bs + ro + (m - q * mb);
}

// ---------------- GEMM: C[m,n] = act(sum_k X[row(m)*ldx+k] * W[n*K+k] + bias[n])
__global__ __launch_bounds__(256) void gemm_kernel(
    const float* __restrict__ X, int ldx, int mb, int bstride, int roff,
    const float* __restrict__ W, const float* __restrict__ bias,
    float* __restrict__ C, int M, int N, int K, int act)
{
    __shared__ float Xs[16][64 + 4];
    __shared__ float Ws[16][64 + 4];
    int tid = threadIdx.x;
    int m0 = blockIdx.y * 64;
    int n0 = blockIdx.x * 64;
    int tx = tid & 15, ty = tid >> 4;
    float acc[4][4] = {};
    for (int k0 = 0; k0 < K; k0 += 16) {
        #pragma unroll
        for (int i = 0; i < 4; i++) {
            int idx = tid + i * 256;
            int kk = idx & 15, mm = idx >> 4;
            int row = map_row(m0 + mm, mb, bstride, roff);
            Xs[kk][mm] = X[(size_t)row * ldx + k0 + kk];
            Ws[kk][mm] = W[(size_t)(n0 + mm) * K + k0 + kk];
        }
        __syncthreads();
        #pragma unroll
        for (int kk = 0; kk < 16; kk++) {
            float a[4], b[4];
            #pragma unroll
            for (int i = 0; i < 4; i++) a[i] = Xs[kk][ty * 4 + i];
            #pragma unroll
            for (int j = 0; j < 4; j++) b[j] = Ws[kk][tx * 4 + j];
            #pragma unroll
            for (int i = 0; i < 4; i++)
                #pragma unroll
                for (int j = 0; j < 4; j++)
                    acc[i][j] = fmaf(a[i], b[j], acc[i][j]);
        }
        __syncthreads();
    }
    #pragma unroll
    for (int i = 0; i < 4; i++) {
        int m = m0 + ty * 4 + i;
        float4 o;
        float* po = &o.x;
        #pragma unroll
        for (int j = 0; j < 4; j++) {
            int n = n0 + tx * 4 + j;
            float v = acc[i][j];
            if (bias) v += bias[n];
            if (act == ACT_RELU) v = v > 0.f ? v : 0.f;
            else if (act == ACT_SOFTPLUS) v = (v > 20.f) ? v : log1pf(__expf(v));
            po[j] = v;
        }
        *((float4*)(C + (size_t)m * N + n0 + tx * 4)) = o;
    }
}

// ---------------- Depthwise causal conv (width 4) + bias + SiLU
// in: xz rows (b*L+l) stride 2048, cols 0..1023.  out: xc rows stride 1024.
__global__ void conv_silu_kernel(const float* __restrict__ xz,
                                 const float* __restrict__ cw,
                                 const float* __restrict__ cb,
                                 float* __restrict__ xc, int L, int total)
{
    int idx = blockIdx.x * blockDim.x + threadIdx.x;
    if (idx >= total) return;
    int d = idx & (DI - 1);
    int r = idx >> 10;     // b*L + l
    int l = r % L;
    float acc = cb[d];
    #pragma unroll
    for (int k = 0; k < 4; k++) {
        int ls = l - 3 + k;
        if (ls >= 0) acc = fmaf(xz[(size_t)(r - 3 + k) * 2048 + d], cw[d * 4 + k], acc);
    }
    float s = acc / (1.f + __expf(-acc));
    xc[idx] = s;
}

// ---------------- Selective scan, fused D_vec skip + z*silu(z) gating.
// one thread per (b,d). out may alias delta (same element read then written).
__global__ __launch_bounds__(128) void scan_kernel(
    const float* __restrict__ delta, const float* __restrict__ xc,
    const float* __restrict__ xdbl, const float* __restrict__ xz,
    const float* __restrict__ A_log, const float* __restrict__ Dv,
    float* __restrict__ out, int L)
{
    int b = blockIdx.x >> 3;
    int d = (blockIdx.x & 7) * 128 + threadIdx.x;
    float A[DSN];
    #pragma unroll
    for (int s = 0; s < DSN; s++) A[s] = -__expf(A_log[d * DSN + s]);
    float Dvd = Dv[d];
    float h[DSN];
    #pragma unroll
    for (int s = 0; s < DSN; s++) h[s] = 0.f;
    for (int l = 0; l < L; l++) {
        size_t r = (size_t)b * L + l;
        const float4* bc = (const float4*)(xdbl + r * 64 + 32);
        float4 bq[8];
        #pragma unroll
        for (int q = 0; q < 8; q++) bq[q] = bc[q];
        const float* Bm = (const float*)&bq[0];
        const float* Cm = Bm + 16;
        float dl = delta[r * DI + d];
        float u  = xc[r * DI + d];
        float du = dl * u;
        float y = 0.f;
        #pragma unroll
        for (int s = 0; s < DSN; s++) {
            float dA = __expf(dl * A[s]);
            h[s] = fmaf(dA, h[s], du * Bm[s]);
            y = fmaf(h[s], Cm[s], y);
        }
        float z = xz[r * 2048 + DI + d];
        float sil = z / (1.f + __expf(-z));
        out[r * DI + d] = (y + u * Dvd) * sil;
    }
}

// ---------------- residual add + LayerNorm over 512, 128 threads x float4
__global__ __launch_bounds__(128) void addln_kernel(
    const float* __restrict__ a, int amb, int absd, int aro, int lda,
    const float* __restrict__ bsrc,
    const float* __restrict__ g, const float* __restrict__ be,
    float* __restrict__ out, int omb, int obsd, int oro, int ldo)
{
    int m = blockIdx.x, t = threadIdx.x;
    int ar = map_row(m, amb, absd, aro);
    float4 x4 = ((const float4*)(a + (size_t)ar * lda))[t];
    float4 y4 = ((const float4*)(bsrc + (size_t)m * DM))[t];
    float v[4] = {x4.x + y4.x, x4.y + y4.y, x4.z + y4.z, x4.w + y4.w};
    float sum = v[0] + v[1] + v[2] + v[3];
    float sq  = v[0]*v[0] + v[1]*v[1] + v[2]*v[2] + v[3]*v[3];
    #pragma unroll
    for (int o = 32; o > 0; o >>= 1) {
        sum += __shfl_down(sum, o);
        sq  += __shfl_down(sq, o);
    }
    __shared__ float s0[2], s1[2];
    if ((t & 63) == 0) { s0[t >> 6] = sum; s1[t >> 6] = sq; }
    __syncthreads();
    float tot = s0[0] + s0[1];
    float tsq = s1[0] + s1[1];
    float mu = tot * (1.f / DM);
    float var = tsq * (1.f / DM) - mu * mu;
    float rs = rsqrtf(var + 1e-6f);
    float4 g4 = ((const float4*)g)[t];
    float4 b4 = ((const float4*)be)[t];
    float4 o4;
    o4.x = (v[0] - mu) * rs * g4.x + b4.x;
    o4.y = (v[1] - mu) * rs * g4.y + b4.y;
    o4.z = (v[2] - mu) * rs * g4.z + b4.z;
    o4.w = (v[3] - mu) * rs * g4.w + b4.w;
    int orow = map_row(m, omb, obsd, oro);
    ((float4*)(out + (size_t)orow * ldo))[t] = o4;
}

// ---------------- memory -> cat[:, :1024, :]
__global__ void copy_mem_kernel(const float* __restrict__ mem, float* __restrict__ cat)
{
    int f = blockIdx.x * blockDim.x + threadIdx.x;
    const int total = BB * TTM * DM / 4;
    if (f >= total) return;
    const int per_b = TTM * DM / 4;
    int b = f / per_b, rem = f - b * per_b;
    ((float4*)cat)[(size_t)b * (LCAT * DM / 4) + rem] = ((const float4*)mem)[f];
}

extern "C" void kernel_launch(void* const* d_in, const int* in_sizes, int n_in,
                              void* d_out, int out_size, void* d_ws, size_t ws_size,
                              hipStream_t stream)
{
    const float* tgt       = (const float*)d_in[0];
    const float* memory    = (const float*)d_in[1];
    const float* s_in_w    = (const float*)d_in[2];
    const float* s_conv_w  = (const float*)d_in[3];
    const float* s_conv_b  = (const float*)d_in[4];
    const float* s_xproj_w = (const float*)d_in[5];
    const float* s_dt_w    = (const float*)d_in[6];
    const float* s_dt_b    = (const float*)d_in[7];
    const float* s_A_log   = (const float*)d_in[8];
    const float* s_D_vec   = (const float*)d_in[9];
    const float* s_out_w   = (const float*)d_in[10];
    const float* c_in_w    = (const float*)d_in[11];
    const float* c_conv_w  = (const float*)d_in[12];
    const float* c_conv_b  = (const float*)d_in[13];
    const float* c_xproj_w = (const float*)d_in[14];
    const float* c_dt_w    = (const float*)d_in[15];
    const float* c_dt_b    = (const float*)d_in[16];
    const float* c_A_log   = (const float*)d_in[17];
    const float* c_D_vec   = (const float*)d_in[18];
    const float* c_out_w   = (const float*)d_in[19];
    const float* ln1_g     = (const float*)d_in[20];
    const float* ln1_b     = (const float*)d_in[21];
    const float* ln2_g     = (const float*)d_in[22];
    const float* ln2_b     = (const float*)d_in[23];
    const float* ln3_g     = (const float*)d_in[24];
    const float* ln3_b     = (const float*)d_in[25];
    const float* ffn_w1    = (const float*)d_in[26];
    const float* ffn_b1    = (const float*)d_in[27];
    const float* ffn_w2    = (const float*)d_in[28];
    const float* ffn_b2    = (const float*)d_in[29];
    float* outp = (float*)d_out;

    // workspace layout (floats); total 61,603,840 floats = 246.4 MB
    float* ws   = (float*)d_ws;
    float* cat  = ws;                       // 8*1536*512   = 6291456
    float* xz   = cat  + 6291456;           // 8*1536*2048  = 25165824
    float* xc   = xz   + 25165824;          // 8*1536*1024  = 12582912
    float* xdbl = xc   + 12582912;          // 8*1536*64    = 786432
    float* dlt  = xdbl + 786432;            // 8*1536*1024  = 12582912 (also ygate)
    float* proj = dlt  + 12582912;          // 8*512*512    = 2097152
    float* tbuf = proj + 2097152;           // 8*512*512    = 2097152
    float* fbuf   = xz;                     // alias: FFN hidden (8*512*2048)
    float* ffnout = xc;                     // alias: FFN out   (8*512*512)

    // memory -> cat
    copy_mem_kernel<<<(BB * TTM * DM / 4 + 255) / 256, 256, 0, stream>>>(memory, cat);

    // ---- self mamba (L=512, M=4096) ----
    gemm_kernel<<<dim3(2048 / 64, 4096 / 64), 256, 0, stream>>>(
        tgt, DM, 4096, 0, 0, s_in_w, nullptr, xz, 4096, 2048, 512, ACT_NONE);
    {
        int total = BB * SS * DI;
        conv_silu_kernel<<<(total + 255) / 256, 256, 0, stream>>>(xz, s_conv_w, s_conv_b, xc, SS, total);
    }
    gemm_kernel<<<dim3(1, 4096 / 64), 256, 0, stream>>>(
        xc, DI, 4096, 0, 0, s_xproj_w, nullptr, xdbl, 4096, 64, 1024, ACT_NONE);
    gemm_kernel<<<dim3(1024 / 64, 4096 / 64), 256, 0, stream>>>(
        xdbl, 64, 4096, 0, 0, s_dt_w, s_dt_b, dlt, 4096, 1024, 32, ACT_SOFTPLUS);
    scan_kernel<<<64, 128, 0, stream>>>(dlt, xc, xdbl, xz, s_A_log, s_D_vec, dlt, SS);
    gemm_kernel<<<dim3(512 / 64, 4096 / 64), 256, 0, stream>>>(
        dlt, DI, 4096, 0, 0, s_out_w, nullptr, proj, 4096, 512, 1024, ACT_NONE);
    // t = LN(tgt + proj) -> write into cat rows [b*1536+1024+l]
    addln_kernel<<<4096, 128, 0, stream>>>(
        tgt, 4096, 0, 0, DM, proj, ln1_g, ln1_b, cat, 512, 1536, 1024, DM);

    // ---- cross mamba (L=1536, M=12288) ----
    gemm_kernel<<<dim3(2048 / 64, 12288 / 64), 256, 0, stream>>>(
        cat, DM, 12288, 0, 0, c_in_w, nullptr, xz, 12288, 2048, 512, ACT_NONE);
    {
        int total = BB * LCAT * DI;
        conv_silu_kernel<<<(total + 255) / 256, 256, 0, stream>>>(xz, c_conv_w, c_conv_b, xc, LCAT, total);
    }
    gemm_kernel<<<dim3(1, 12288 / 64), 256, 0, stream>>>(
        xc, DI, 12288, 0, 0, c_xproj_w, nullptr, xdbl, 12288, 64, 1024, ACT_NONE);
    gemm_kernel<<<dim3(1024 / 64, 12288 / 64), 256, 0, stream>>>(
        xdbl, 64, 12288, 0, 0, c_dt_w, c_dt_b, dlt, 12288, 1024, 32, ACT_SOFTPLUS);
    scan_kernel<<<64, 128, 0, stream>>>(dlt, xc, xdbl, xz, c_A_log, c_D_vec, dlt, LCAT);
    // out proj only over last S rows per batch: row(m) = (m/512)*1536 + 1024 + m%512
    gemm_kernel<<<dim3(512 / 64, 4096 / 64), 256, 0, stream>>>(
        dlt, DI, 512, 1536, 1024, c_out_w, nullptr, proj, 4096, 512, 1024, ACT_NONE);
    // t = LN(t + c2); a read from cat (mapped), out -> tbuf
    addln_kernel<<<4096, 128, 0, stream>>>(
        cat, 512, 1536, 1024, DM, proj, ln2_g, ln2_b, tbuf, 4096, 0, 0, DM);

    // ---- FFN ----
    gemm_kernel<<<dim3(2048 / 64, 4096 / 64), 256, 0, stream>>>(
        tbuf, DM, 4096, 0, 0, ffn_w1, ffn_b1, fbuf, 4096, 2048, 512, ACT_RELU);
    gemm_kernel<<<dim3(512 / 64, 4096 / 64), 256, 0, stream>>>(
        fbuf, DFFN, 4096, 0, 0, ffn_w2, ffn_b2, ffnout, 4096, 512, 2048, ACT_NONE);
    addln_kernel<<<4096, 128, 0, stream>>>(
        tbuf, 4096, 0, 0, DM, ffnout, ln3_g, ln3_b, outp, 4096, 0, 0, DM);
}

// Round 2
// 1561.381 us; speedup vs baseline: 1.4988x; 1.4988x over previous
//
#include <hip/hip_runtime.h>
#include <hip/hip_bf16.h>
#include <math.h>

// Problem constants
#define DM    512
#define DI    1024
#define DSN   16
#define DCONV 4
#define DTR   32
#define DFFN  2048
#define BB    8
#define SS    512
#define TTM   1024
#define LCAT  1536
#define NC    32      // scan chunks per sequence

#define ACT_NONE     0
#define ACT_RELU     1
#define ACT_SOFTPLUS 2

__device__ __forceinline__ int map_row(int m, int mb, int bs, int ro) {
    int q = m / mb;
    return q * bs + ro + (m - q * mb);
}

// ---------------- GEMM: C[m,n] = act(sum_k X[row(m)*ldx+k] * W[n*K+k] + bias[n])
__global__ __launch_bounds__(256) void gemm_kernel(
    const float* __restrict__ X, int ldx, int mb, int bstride, int roff,
    const float* __restrict__ W, const float* __restrict__ bias,
    float* __restrict__ C, int M, int N, int K, int act)
{
    __shared__ float Xs[16][64 + 4];
    __shared__ float Ws[16][64 + 4];
    int tid = threadIdx.x;
    int m0 = blockIdx.y * 64;
    int n0 = blockIdx.x * 64;
    int tx = tid & 15, ty = tid >> 4;
    float acc[4][4] = {};
    for (int k0 = 0; k0 < K; k0 += 16) {
        #pragma unroll
        for (int i = 0; i < 4; i++) {
            int idx = tid + i * 256;
            int kk = idx & 15, mm = idx >> 4;
            int row = map_row(m0 + mm, mb, bstride, roff);
            Xs[kk][mm] = X[(size_t)row * ldx + k0 + kk];
            Ws[kk][mm] = W[(size_t)(n0 + mm) * K + k0 + kk];
        }
        __syncthreads();
        #pragma unroll
        for (int kk = 0; kk < 16; kk++) {
            float a[4], b[4];
            #pragma unroll
            for (int i = 0; i < 4; i++) a[i] = Xs[kk][ty * 4 + i];
            #pragma unroll
            for (int j = 0; j < 4; j++) b[j] = Ws[kk][tx * 4 + j];
            #pragma unroll
            for (int i = 0; i < 4; i++)
                #pragma unroll
                for (int j = 0; j < 4; j++)
                    acc[i][j] = fmaf(a[i], b[j], acc[i][j]);
        }
        __syncthreads();
    }
    #pragma unroll
    for (int i = 0; i < 4; i++) {
        int m = m0 + ty * 4 + i;
        float4 o;
        float* po = &o.x;
        #pragma unroll
        for (int j = 0; j < 4; j++) {
            int n = n0 + tx * 4 + j;
            float v = acc[i][j];
            if (bias) v += bias[n];
            if (act == ACT_RELU) v = v > 0.f ? v : 0.f;
            else if (act == ACT_SOFTPLUS) v = (v > 20.f) ? v : log1pf(__expf(v));
            po[j] = v;
        }
        *((float4*)(C + (size_t)m * N + n0 + tx * 4)) = o;
    }
}

// ---------------- Depthwise causal conv (width 4) + bias + SiLU
__global__ void conv_silu_kernel(const float* __restrict__ xz,
                                 const float* __restrict__ cw,
                                 const float* __restrict__ cb,
                                 float* __restrict__ xc, int L, int total)
{
    int idx = blockIdx.x * blockDim.x + threadIdx.x;
    if (idx >= total) return;
    int d = idx & (DI - 1);
    int r = idx >> 10;     // b*L + l
    int l = r % L;
    float acc = cb[d];
    #pragma unroll
    for (int k = 0; k < 4; k++) {
        int ls = l - 3 + k;
        if (ls >= 0) acc = fmaf(xz[(size_t)(r - 3 + k) * 2048 + d], cw[d * 4 + k], acc);
    }
    float s = acc / (1.f + __expf(-acc));
    xc[idx] = s;
}

// ---------------- Chunked selective scan, pass 1: per-chunk local scan (h from 0)
// grid: BB * NC * (DI/256) blocks x 256.  Writes part_h[(b*NC+c)*DI+d][16], part_s.
__global__ __launch_bounds__(256) void scan_part1(
    const float* __restrict__ delta, const float* __restrict__ xc,
    const float* __restrict__ xdbl, const float* __restrict__ A_log,
    float* __restrict__ part_h, float* __restrict__ part_s, int L, int CH)
{
    int tid = threadIdx.x;
    int dblk = blockIdx.x & 3;
    int c    = (blockIdx.x >> 2) & (NC - 1);
    int b    = blockIdx.x >> 7;
    int d    = dblk * 256 + tid;
    float A[DSN];
    #pragma unroll
    for (int s = 0; s < DSN; s++) A[s] = -__expf(A_log[d * DSN + s]);
    float h[DSN];
    #pragma unroll
    for (int s = 0; s < DSN; s++) h[s] = 0.f;
    float ssum = 0.f;
    int l0 = c * CH;
    for (int l = l0; l < l0 + CH; l++) {
        size_t r = (size_t)b * L + l;
        float4 bq[4];
        const float4* bp = (const float4*)(xdbl + r * 64 + 32);
        #pragma unroll
        for (int q = 0; q < 4; q++) bq[q] = bp[q];
        const float* Bm = (const float*)&bq[0];
        float dl = delta[r * DI + d];
        float u  = xc[r * DI + d];
        float du = dl * u;
        ssum += dl;
        #pragma unroll
        for (int s = 0; s < DSN; s++)
            h[s] = fmaf(__expf(dl * A[s]), h[s], du * Bm[s]);
    }
    size_t base = ((size_t)(b * NC + c) * DI + d) * DSN;
    #pragma unroll
    for (int q = 0; q < 4; q++)
        ((float4*)(part_h + base))[q] = make_float4(h[q*4], h[q*4+1], h[q*4+2], h[q*4+3]);
    part_s[(size_t)(b * NC + c) * DI + d] = ssum;
}

// ---------------- pass 2: sequential chunk combine per (b,d); part_h becomes h_in.
__global__ __launch_bounds__(256) void scan_combine(
    const float* __restrict__ A_log,
    float* __restrict__ part_h, const float* __restrict__ part_s)
{
    int idx = blockIdx.x * 256 + threadIdx.x;
    int b = idx >> 10, d = idx & (DI - 1);
    float A[DSN];
    #pragma unroll
    for (int s = 0; s < DSN; s++) A[s] = -__expf(A_log[d * DSN + s]);
    float h[DSN];
    #pragma unroll
    for (int s = 0; s < DSN; s++) h[s] = 0.f;
    for (int c = 0; c < NC; c++) {
        size_t base = ((size_t)(b * NC + c) * DI + d) * DSN;
        float4 ph4[4];
        #pragma unroll
        for (int q = 0; q < 4; q++) ph4[q] = ((const float4*)(part_h + base))[q];
        const float* ph = (const float*)&ph4[0];
        float S = part_s[(size_t)(b * NC + c) * DI + d];
        #pragma unroll
        for (int q = 0; q < 4; q++)
            ((float4*)(part_h + base))[q] = make_float4(h[q*4], h[q*4+1], h[q*4+2], h[q*4+3]);
        #pragma unroll
        for (int s = 0; s < DSN; s++)
            h[s] = fmaf(__expf(A[s] * S), h[s], ph[s]);
    }
}

// ---------------- pass 3: rescan chunk from h_in, emit gated output.
// out aliases delta (per-element read-then-write by the owning thread only).
__global__ __launch_bounds__(256) void scan_part2(
    const float* __restrict__ delta, const float* __restrict__ xc,
    const float* __restrict__ xdbl, const float* __restrict__ xz,
    const float* __restrict__ A_log, const float* __restrict__ Dv,
    const float* __restrict__ part_h,
    float* __restrict__ out, int L, int CH)
{
    int tid = threadIdx.x;
    int dblk = blockIdx.x & 3;
    int c    = (blockIdx.x >> 2) & (NC - 1);
    int b    = blockIdx.x >> 7;
    int d    = dblk * 256 + tid;
    float A[DSN];
    #pragma unroll
    for (int s = 0; s < DSN; s++) A[s] = -__expf(A_log[d * DSN + s]);
    float Dvd = Dv[d];
    size_t base = ((size_t)(b * NC + c) * DI + d) * DSN;
    float h4[4][4];
    #pragma unroll
    for (int q = 0; q < 4; q++) *((float4*)h4[q]) = ((const float4*)(part_h + base))[q];
    float h[DSN];
    #pragma unroll
    for (int s = 0; s < DSN; s++) h[s] = h4[s >> 2][s & 3];
    int l0 = c * CH;
    for (int l = l0; l < l0 + CH; l++) {
        size_t r = (size_t)b * L + l;
        float4 bq[8];
        const float4* bp = (const float4*)(xdbl + r * 64 + 32);
        #pragma unroll
        for (int q = 0; q < 8; q++) bq[q] = bp[q];
        const float* Bm = (const float*)&bq[0];
        const float* Cm = Bm + DSN;
        float dl = delta[r * DI + d];
        float u  = xc[r * DI + d];
        float du = dl * u;
        float y = 0.f;
        #pragma unroll
        for (int s = 0; s < DSN; s++) {
            h[s] = fmaf(__expf(dl * A[s]), h[s], du * Bm[s]);
            y = fmaf(h[s], Cm[s], y);
        }
        float z = xz[r * 2048 + DI + d];
        float sil = z / (1.f + __expf(-z));
        out[r * DI + d] = (y + u * Dvd) * sil;
    }
}

// ---------------- residual add + LayerNorm over 512, 128 threads x float4
__global__ __launch_bounds__(128) void addln_kernel(
    const float* __restrict__ a, int amb, int absd, int aro, int lda,
    const float* __restrict__ bsrc,
    const float* __restrict__ g, const float* __restrict__ be,
    float* __restrict__ out, int omb, int obsd, int oro, int ldo)
{
    int m = blockIdx.x, t = threadIdx.x;
    int ar = map_row(m, amb, absd, aro);
    float4 x4 = ((const float4*)(a + (size_t)ar * lda))[t];
    float4 y4 = ((const float4*)(bsrc + (size_t)m * DM))[t];
    float v[4] = {x4.x + y4.x, x4.y + y4.y, x4.z + y4.z, x4.w + y4.w};
    float sum = v[0] + v[1] + v[2] + v[3];
    float sq  = v[0]*v[0] + v[1]*v[1] + v[2]*v[2] + v[3]*v[3];
    #pragma unroll
    for (int o = 32; o > 0; o >>= 1) {
        sum += __shfl_down(sum, o);
        sq  += __shfl_down(sq, o);
    }
    __shared__ float s0[2], s1[2];
    if ((t & 63) == 0) { s0[t >> 6] = sum; s1[t >> 6] = sq; }
    __syncthreads();
    float tot = s0[0] + s0[1];
    float tsq = s1[0] + s1[1];
    float mu = tot * (1.f / DM);
    float var = tsq * (1.f / DM) - mu * mu;
    float rs = rsqrtf(var + 1e-6f);
    float4 g4 = ((const float4*)g)[t];
    float4 b4 = ((const float4*)be)[t];
    float4 o4;
    o4.x = (v[0] - mu) * rs * g4.x + b4.x;
    o4.y = (v[1] - mu) * rs * g4.y + b4.y;
    o4.z = (v[2] - mu) * rs * g4.z + b4.z;
    o4.w = (v[3] - mu) * rs * g4.w + b4.w;
    int orow = map_row(m, omb, obsd, oro);
    ((float4*)(out + (size_t)orow * ldo))[t] = o4;
}

// ---------------- memory -> cat[:, :1024, :]
__global__ void copy_mem_kernel(const float* __restrict__ mem, float* __restrict__ cat)
{
    int f = blockIdx.x * blockDim.x + threadIdx.x;
    const int total = BB * TTM * DM / 4;
    if (f >= total) return;
    const int per_b = TTM * DM / 4;
    int b = f / per_b, rem = f - b * per_b;
    ((float4*)cat)[(size_t)b * (LCAT * DM / 4) + rem] = ((const float4*)mem)[f];
}

static void run_scan(const float* dlt, const float* xc, const float* xdbl,
                     const float* xz, const float* A_log, const float* Dv,
                     float* part_h, float* part_s, float* out, int L,
                     hipStream_t stream)
{
    int CH = L / NC;
    int blocks = BB * NC * (DI / 256);
    scan_part1<<<blocks, 256, 0, stream>>>(dlt, xc, xdbl, A_log, part_h, part_s, L, CH);
    scan_combine<<<BB * DI / 256, 256, 0, stream>>>(A_log, part_h, part_s);
    scan_part2<<<blocks, 256, 0, stream>>>(dlt, xc, xdbl, xz, A_log, Dv, part_h, out, L, CH);
}

extern "C" void kernel_launch(void* const* d_in, const int* in_sizes, int n_in,
                              void* d_out, int out_size, void* d_ws, size_t ws_size,
                              hipStream_t stream)
{
    const float* tgt       = (const float*)d_in[0];
    const float* memory    = (const float*)d_in[1];
    const float* s_in_w    = (const float*)d_in[2];
    const float* s_conv_w  = (const float*)d_in[3];
    const float* s_conv_b  = (const float*)d_in[4];
    const float* s_xproj_w = (const float*)d_in[5];
    const float* s_dt_w    = (const float*)d_in[6];
    const float* s_dt_b    = (const float*)d_in[7];
    const float* s_A_log   = (const float*)d_in[8];
    const float* s_D_vec   = (const float*)d_in[9];
    const float* s_out_w   = (const float*)d_in[10];
    const float* c_in_w    = (const float*)d_in[11];
    const float* c_conv_w  = (const float*)d_in[12];
    const float* c_conv_b  = (const float*)d_in[13];
    const float* c_xproj_w = (const float*)d_in[14];
    const float* c_dt_w    = (const float*)d_in[15];
    const float* c_dt_b    = (const float*)d_in[16];
    const float* c_A_log   = (const float*)d_in[17];
    const float* c_D_vec   = (const float*)d_in[18];
    const float* c_out_w   = (const float*)d_in[19];
    const float* ln1_g     = (const float*)d_in[20];
    const float* ln1_b     = (const float*)d_in[21];
    const float* ln2_g     = (const float*)d_in[22];
    const float* ln2_b     = (const float*)d_in[23];
    const float* ln3_g     = (const float*)d_in[24];
    const float* ln3_b     = (const float*)d_in[25];
    const float* ffn_w1    = (const float*)d_in[26];
    const float* ffn_b1    = (const float*)d_in[27];
    const float* ffn_w2    = (const float*)d_in[28];
    const float* ffn_b2    = (const float*)d_in[29];
    float* outp = (float*)d_out;

    // workspace layout (floats)
    float* ws     = (float*)d_ws;
    float* cat    = ws;                     // 8*1536*512   = 6291456
    float* xz     = cat  + 6291456;         // 8*1536*2048  = 25165824
    float* xc     = xz   + 25165824;        // 8*1536*1024  = 12582912
    float* xdbl   = xc   + 12582912;        // 8*1536*64    = 786432
    float* dlt    = xdbl + 786432;          // 8*1536*1024  = 12582912 (also ygate)
    float* proj   = dlt  + 12582912;        // 8*512*512    = 2097152
    float* tbuf   = proj + 2097152;         // 8*512*512    = 2097152
    float* part_h = tbuf + 2097152;         // 8*32*1024*16 = 4194304
    float* part_s = part_h + 4194304;       // 8*32*1024    = 262144
    float* fbuf   = xz;                     // alias: FFN hidden (8*512*2048)
    float* ffnout = xc;                     // alias: FFN out   (8*512*512)

    // memory -> cat
    copy_mem_kernel<<<(BB * TTM * DM / 4 + 255) / 256, 256, 0, stream>>>(memory, cat);

    // ---- self mamba (L=512, M=4096) ----
    gemm_kernel<<<dim3(2048 / 64, 4096 / 64), 256, 0, stream>>>(
        tgt, DM, 4096, 0, 0, s_in_w, nullptr, xz, 4096, 2048, 512, ACT_NONE);
    {
        int total = BB * SS * DI;
        conv_silu_kernel<<<(total + 255) / 256, 256, 0, stream>>>(xz, s_conv_w, s_conv_b, xc, SS, total);
    }
    gemm_kernel<<<dim3(1, 4096 / 64), 256, 0, stream>>>(
        xc, DI, 4096, 0, 0, s_xproj_w, nullptr, xdbl, 4096, 64, 1024, ACT_NONE);
    gemm_kernel<<<dim3(1024 / 64, 4096 / 64), 256, 0, stream>>>(
        xdbl, 64, 4096, 0, 0, s_dt_w, s_dt_b, dlt, 4096, 1024, 32, ACT_SOFTPLUS);
    run_scan(dlt, xc, xdbl, xz, s_A_log, s_D_vec, part_h, part_s, dlt, SS, stream);
    gemm_kernel<<<dim3(512 / 64, 4096 / 64), 256, 0, stream>>>(
        dlt, DI, 4096, 0, 0, s_out_w, nullptr, proj, 4096, 512, 1024, ACT_NONE);
    // t = LN(tgt + proj) -> write into cat rows [b*1536+1024+l]
    addln_kernel<<<4096, 128, 0, stream>>>(
        tgt, 4096, 0, 0, DM, proj, ln1_g, ln1_b, cat, 512, 1536, 1024, DM);

    // ---- cross mamba (L=1536, M=12288) ----
    gemm_kernel<<<dim3(2048 / 64, 12288 / 64), 256, 0, stream>>>(
        cat, DM, 12288, 0, 0, c_in_w, nullptr, xz, 12288, 2048, 512, ACT_NONE);
    {
        int total = BB * LCAT * DI;
        conv_silu_kernel<<<(total + 255) / 256, 256, 0, stream>>>(xz, c_conv_w, c_conv_b, xc, LCAT, total);
    }
    gemm_kernel<<<dim3(1, 12288 / 64), 256, 0, stream>>>(
        xc, DI, 12288, 0, 0, c_xproj_w, nullptr, xdbl, 12288, 64, 1024, ACT_NONE);
    gemm_kernel<<<dim3(1024 / 64, 12288 / 64), 256, 0, stream>>>(
        xdbl, 64, 12288, 0, 0, c_dt_w, c_dt_b, dlt, 12288, 1024, 32, ACT_SOFTPLUS);
    run_scan(dlt, xc, xdbl, xz, c_A_log, c_D_vec, part_h, part_s, dlt, LCAT, stream);
    // out proj only over last S rows per batch
    gemm_kernel<<<dim3(512 / 64, 4096 / 64), 256, 0, stream>>>(
        dlt, DI, 512, 1536, 1024, c_out_w, nullptr, proj, 4096, 512, 1024, ACT_NONE);
    addln_kernel<<<4096, 128, 0, stream>>>(
        cat, 512, 1536, 1024, DM, proj, ln2_g, ln2_b, tbuf, 4096, 0, 0, DM);

    // ---- FFN ----
    gemm_kernel<<<dim3(2048 / 64, 4096 / 64), 256, 0, stream>>>(
        tbuf, DM, 4096, 0, 0, ffn_w1, ffn_b1, fbuf, 4096, 2048, 512, ACT_RELU);
    gemm_kernel<<<dim3(512 / 64, 4096 / 64), 256, 0, stream>>>(
        fbuf, DFFN, 4096, 0, 0, ffn_w2, ffn_b2, ffnout, 4096, 512, 2048, ACT_NONE);
    addln_kernel<<<4096, 128, 0, stream>>>(
        tbuf, 4096, 0, 0, DM, ffnout, ln3_g, ln3_b, outp, 4096, 0, 0, DM);
}

// Round 3
// 844.389 us; speedup vs baseline: 2.7716x; 1.8491x over previous
//
#include <hip/hip_runtime.h>
#include <math.h>

// Problem constants
#define DM    512
#define DI    1024
#define DSN   16
#define DTR   32
#define DFFN  2048
#define BB    8
#define SS    512
#define TTM   1024
#define LCAT  1536
#define NC    32      // scan chunks per sequence

#define ACT_NONE     0
#define ACT_RELU     1
#define ACT_SOFTPLUS 2

typedef __attribute__((ext_vector_type(8))) short short8;
typedef __attribute__((ext_vector_type(4))) float f32x4;

__device__ __forceinline__ unsigned short f2b(float f) {
    unsigned int u = __float_as_uint(f);
    return (unsigned short)((u + 0x7FFFu + ((u >> 16) & 1u)) >> 16);
}
__device__ __forceinline__ float b2f(unsigned short h) {
    return __uint_as_float(((unsigned int)h) << 16);
}
__device__ __forceinline__ void gld16(const void* g, void* l) {
    __builtin_amdgcn_global_load_lds(
        (const __attribute__((address_space(1))) void*)g,
        (__attribute__((address_space(3))) void*)l, 16, 0, 0);
}

__device__ __forceinline__ int map_row(int m, int mb, int bs, int ro) {
    int q = m / mb;
    return q * bs + ro + (m - q * mb);
}

// ================= bf16 MFMA GEMM: C[m,n] = act(A[row(m),k] * W[n,k] + bias[n])
// A: bf16, row stride K. W: bf16, N x K row-major. Tile 128x128, BK=32.
__global__ __launch_bounds__(256) void mgemm_kernel(
    const unsigned short* __restrict__ A, int mb, int bs, int ro,
    const unsigned short* __restrict__ W, const float* __restrict__ bias,
    float* __restrict__ Cf, unsigned short* __restrict__ Cb,
    int N, int K, int act)
{
    __shared__ __align__(16) unsigned short As[128 * 32];
    __shared__ __align__(16) unsigned short Bs[128 * 32];
    int tid = threadIdx.x;
    int lane = tid & 63, wave = tid >> 6;
    int wy = wave >> 1, wx = wave & 1;
    int m0 = blockIdx.y * 128, n0 = blockIdx.x * 128;

    // staging: per wave, 2 groups of 16 rows for A and for B. lane r=lane>>2 row,
    // (lane&3)*8 bf16 col offset -> 16B per lane, LDS lands row-major [128][32].
    int sr = lane >> 2;
    int sc = (lane & 3) * 8;
    const unsigned short* ga[2];
    const unsigned short* gb[2];
    unsigned short* la[2];
    unsigned short* lb[2];
    #pragma unroll
    for (int j = 0; j < 2; j++) {
        int r = wave * 32 + j * 16 + sr;
        int gr = map_row(m0 + r, mb, bs, ro);
        ga[j] = A + (size_t)gr * K + sc;
        gb[j] = W + (size_t)(n0 + wave * 32 + j * 16 + sr) * K + sc;
        la[j] = As + (wave * 32 + j * 16) * 32;
        lb[j] = Bs + (wave * 32 + j * 16) * 32;
    }
    int fm = lane & 15;
    int fk = (lane >> 4) * 8;
    const unsigned short* arp = As + (wy * 64 + fm) * 32 + fk;
    const unsigned short* brp = Bs + (wx * 64 + fm) * 32 + fk;

    f32x4 acc[4][4];
    #pragma unroll
    for (int i = 0; i < 4; i++)
        #pragma unroll
        for (int j = 0; j < 4; j++) acc[i][j] = 0.f;

    for (int k0 = 0; k0 < K; k0 += 32) {
        #pragma unroll
        for (int j = 0; j < 2; j++) {
            gld16(ga[j] + k0, la[j]);
            gld16(gb[j] + k0, lb[j]);
        }
        __syncthreads();
        short8 af[4], bfr[4];
        #pragma unroll
        for (int t = 0; t < 4; t++) af[t]  = *(const short8*)(arp + t * 16 * 32);
        #pragma unroll
        for (int t = 0; t < 4; t++) bfr[t] = *(const short8*)(brp + t * 16 * 32);
        #pragma unroll
        for (int i = 0; i < 4; i++)
            #pragma unroll
            for (int j = 0; j < 4; j++)
                acc[i][j] = __builtin_amdgcn_mfma_f32_16x16x32_bf16(af[i], bfr[j], acc[i][j], 0, 0, 0);
        __syncthreads();
    }

    // epilogue: C/D layout col=lane&15 (n), row=(lane>>4)*4+reg (m)
    int en = lane & 15, em = (lane >> 4) * 4;
    #pragma unroll
    for (int j = 0; j < 4; j++) {
        int n = n0 + wx * 64 + j * 16 + en;
        float bv = bias ? bias[n] : 0.f;
        #pragma unroll
        for (int i = 0; i < 4; i++) {
            int mbase = m0 + wy * 64 + i * 16 + em;
            #pragma unroll
            for (int r = 0; r < 4; r++) {
                float v = acc[i][j][r] + bv;
                if (act == ACT_RELU) v = v > 0.f ? v : 0.f;
                size_t off = (size_t)(mbase + r) * N + n;
                if (Cb) Cb[off] = f2b(v);
                else    Cf[off] = v;
            }
        }
    }
}

// ================= fp32 tiled GEMM (kept for xproj N=64 / dt-proj K=32)
__global__ __launch_bounds__(256) void gemm_kernel(
    const float* __restrict__ X, int ldx, int mb, int bstride, int roff,
    const float* __restrict__ W, const float* __restrict__ bias,
    float* __restrict__ C, int M, int N, int K, int act)
{
    __shared__ float Xs[16][64 + 4];
    __shared__ float Ws[16][64 + 4];
    int tid = threadIdx.x;
    int m0 = blockIdx.y * 64;
    int n0 = blockIdx.x * 64;
    int tx = tid & 15, ty = tid >> 4;
    float acc[4][4] = {};
    for (int k0 = 0; k0 < K; k0 += 16) {
        #pragma unroll
        for (int i = 0; i < 4; i++) {
            int idx = tid + i * 256;
            int kk = idx & 15, mm = idx >> 4;
            int row = map_row(m0 + mm, mb, bstride, roff);
            Xs[kk][mm] = X[(size_t)row * ldx + k0 + kk];
            Ws[kk][mm] = W[(size_t)(n0 + mm) * K + k0 + kk];
        }
        __syncthreads();
        #pragma unroll
        for (int kk = 0; kk < 16; kk++) {
            float a[4], b[4];
            #pragma unroll
            for (int i = 0; i < 4; i++) a[i] = Xs[kk][ty * 4 + i];
            #pragma unroll
            for (int j = 0; j < 4; j++) b[j] = Ws[kk][tx * 4 + j];
            #pragma unroll
            for (int i = 0; i < 4; i++)
                #pragma unroll
                for (int j = 0; j < 4; j++)
                    acc[i][j] = fmaf(a[i], b[j], acc[i][j]);
        }
        __syncthreads();
    }
    #pragma unroll
    for (int i = 0; i < 4; i++) {
        int m = m0 + ty * 4 + i;
        float4 o;
        float* po = &o.x;
        #pragma unroll
        for (int j = 0; j < 4; j++) {
            int n = n0 + tx * 4 + j;
            float v = acc[i][j];
            if (bias) v += bias[n];
            if (act == ACT_RELU) v = v > 0.f ? v : 0.f;
            else if (act == ACT_SOFTPLUS) v = (v > 20.f) ? v : log1pf(__expf(v));
            po[j] = v;
        }
        *((float4*)(C + (size_t)m * N + n0 + tx * 4)) = o;
    }
}

// ================= Depthwise causal conv (width 4) + bias + SiLU. bf16 in, fp32 out.
__global__ void conv_silu_kernel(const unsigned short* __restrict__ xz,
                                 const float* __restrict__ cw,
                                 const float* __restrict__ cb,
                                 float* __restrict__ xc, int L, int total)
{
    int idx = blockIdx.x * blockDim.x + threadIdx.x;
    if (idx >= total) return;
    int d = idx & (DI - 1);
    int r = idx >> 10;     // b*L + l
    int l = r % L;
    float acc = cb[d];
    #pragma unroll
    for (int k = 0; k < 4; k++) {
        int ls = l - 3 + k;
        if (ls >= 0) acc = fmaf(b2f(xz[(size_t)(r - 3 + k) * 2048 + d]), cw[d * 4 + k], acc);
    }
    float s = acc / (1.f + __expf(-acc));
    xc[idx] = s;
}

// ================= Chunked selective scan
__global__ __launch_bounds__(256) void scan_part1(
    const float* __restrict__ delta, const float* __restrict__ xc,
    const float* __restrict__ xdbl, const float* __restrict__ A_log,
    float* __restrict__ part_h, float* __restrict__ part_s, int L, int CH)
{
    int tid = threadIdx.x;
    int dblk = blockIdx.x & 3;
    int c    = (blockIdx.x >> 2) & (NC - 1);
    int b    = blockIdx.x >> 7;
    int d    = dblk * 256 + tid;
    float A[DSN];
    #pragma unroll
    for (int s = 0; s < DSN; s++) A[s] = -__expf(A_log[d * DSN + s]);
    float h[DSN];
    #pragma unroll
    for (int s = 0; s < DSN; s++) h[s] = 0.f;
    float ssum = 0.f;
    int l0 = c * CH;
    for (int l = l0; l < l0 + CH; l++) {
        size_t r = (size_t)b * L + l;
        float4 bq[4];
        const float4* bp = (const float4*)(xdbl + r * 64 + 32);
        #pragma unroll
        for (int q = 0; q < 4; q++) bq[q] = bp[q];
        const float* Bm = (const float*)&bq[0];
        float dl = delta[r * DI + d];
        float u  = xc[r * DI + d];
        float du = dl * u;
        ssum += dl;
        #pragma unroll
        for (int s = 0; s < DSN; s++)
            h[s] = fmaf(__expf(dl * A[s]), h[s], du * Bm[s]);
    }
    size_t base = ((size_t)(b * NC + c) * DI + d) * DSN;
    #pragma unroll
    for (int q = 0; q < 4; q++)
        ((float4*)(part_h + base))[q] = make_float4(h[q*4], h[q*4+1], h[q*4+2], h[q*4+3]);
    part_s[(size_t)(b * NC + c) * DI + d] = ssum;
}

__global__ __launch_bounds__(256) void scan_combine(
    const float* __restrict__ A_log,
    float* __restrict__ part_h, const float* __restrict__ part_s)
{
    int idx = blockIdx.x * 256 + threadIdx.x;
    int b = idx >> 10, d = idx & (DI - 1);
    float A[DSN];
    #pragma unroll
    for (int s = 0; s < DSN; s++) A[s] = -__expf(A_log[d * DSN + s]);
    float h[DSN];
    #pragma unroll
    for (int s = 0; s < DSN; s++) h[s] = 0.f;
    for (int c = 0; c < NC; c++) {
        size_t base = ((size_t)(b * NC + c) * DI + d) * DSN;
        float4 ph4[4];
        #pragma unroll
        for (int q = 0; q < 4; q++) ph4[q] = ((const float4*)(part_h + base))[q];
        const float* ph = (const float*)&ph4[0];
        float S = part_s[(size_t)(b * NC + c) * DI + d];
        #pragma unroll
        for (int q = 0; q < 4; q++)
            ((float4*)(part_h + base))[q] = make_float4(h[q*4], h[q*4+1], h[q*4+2], h[q*4+3]);
        #pragma unroll
        for (int s = 0; s < DSN; s++)
            h[s] = fmaf(__expf(A[s] * S), h[s], ph[s]);
    }
}

// pass 3: rescan chunk from h_in, emit gated output to bf16 buffer.
__global__ __launch_bounds__(256) void scan_part2(
    const float* __restrict__ delta, const float* __restrict__ xc,
    const float* __restrict__ xdbl, const unsigned short* __restrict__ xz,
    const float* __restrict__ A_log, const float* __restrict__ Dv,
    const float* __restrict__ part_h,
    unsigned short* __restrict__ out, int L, int CH)
{
    int tid = threadIdx.x;
    int dblk = blockIdx.x & 3;
    int c    = (blockIdx.x >> 2) & (NC - 1);
    int b    = blockIdx.x >> 7;
    int d    = dblk * 256 + tid;
    float A[DSN];
    #pragma unroll
    for (int s = 0; s < DSN; s++) A[s] = -__expf(A_log[d * DSN + s]);
    float Dvd = Dv[d];
    size_t base = ((size_t)(b * NC + c) * DI + d) * DSN;
    float h4[4][4];
    #pragma unroll
    for (int q = 0; q < 4; q++) *((float4*)h4[q]) = ((const float4*)(part_h + base))[q];
    float h[DSN];
    #pragma unroll
    for (int s = 0; s < DSN; s++) h[s] = h4[s >> 2][s & 3];
    int l0 = c * CH;
    for (int l = l0; l < l0 + CH; l++) {
        size_t r = (size_t)b * L + l;
        float4 bq[8];
        const float4* bp = (const float4*)(xdbl + r * 64 + 32);
        #pragma unroll
        for (int q = 0; q < 8; q++) bq[q] = bp[q];
        const float* Bm = (const float*)&bq[0];
        const float* Cm = Bm + DSN;
        float dl = delta[r * DI + d];
        float u  = xc[r * DI + d];
        float du = dl * u;
        float y = 0.f;
        #pragma unroll
        for (int s = 0; s < DSN; s++) {
            h[s] = fmaf(__expf(dl * A[s]), h[s], du * Bm[s]);
            y = fmaf(h[s], Cm[s], y);
        }
        float z = b2f(xz[r * 2048 + DI + d]);
        float sil = z / (1.f + __expf(-z));
        out[r * DI + d] = f2b((y + u * Dvd) * sil);
    }
}

// ================= residual add + LayerNorm; optional fp32 and bf16 outputs
__global__ __launch_bounds__(128) void addln_kernel(
    const float* __restrict__ a, int amb, int absd, int aro, int lda,
    const float* __restrict__ bsrc,
    const float* __restrict__ g, const float* __restrict__ be,
    float* __restrict__ outf, int omb, int obsd, int oro, int ldo,
    unsigned short* __restrict__ outb, int bmb, int bbsd, int bro, int ldb)
{
    int m = blockIdx.x, t = threadIdx.x;
    int ar = map_row(m, amb, absd, aro);
    float4 x4 = ((const float4*)(a + (size_t)ar * lda))[t];
    float4 y4 = ((const float4*)(bsrc + (size_t)m * DM))[t];
    float v[4] = {x4.x + y4.x, x4.y + y4.y, x4.z + y4.z, x4.w + y4.w};
    float sum = v[0] + v[1] + v[2] + v[3];
    float sq  = v[0]*v[0] + v[1]*v[1] + v[2]*v[2] + v[3]*v[3];
    #pragma unroll
    for (int o = 32; o > 0; o >>= 1) {
        sum += __shfl_down(sum, o);
        sq  += __shfl_down(sq, o);
    }
    __shared__ float s0[2], s1[2];
    if ((t & 63) == 0) { s0[t >> 6] = sum; s1[t >> 6] = sq; }
    __syncthreads();
    float tot = s0[0] + s0[1];
    float tsq = s1[0] + s1[1];
    float mu = tot * (1.f / DM);
    float var = tsq * (1.f / DM) - mu * mu;
    float rs = rsqrtf(var + 1e-6f);
    float4 g4 = ((const float4*)g)[t];
    float4 b4 = ((const float4*)be)[t];
    float o0 = (v[0] - mu) * rs * g4.x + b4.x;
    float o1 = (v[1] - mu) * rs * g4.y + b4.y;
    float o2 = (v[2] - mu) * rs * g4.z + b4.z;
    float o3 = (v[3] - mu) * rs * g4.w + b4.w;
    if (outf) {
        int orow = map_row(m, omb, obsd, oro);
        ((float4*)(outf + (size_t)orow * ldo))[t] = make_float4(o0, o1, o2, o3);
    }
    if (outb) {
        int brow = map_row(m, bmb, bbsd, bro);
        ((ushort4*)(outb + (size_t)brow * ldb))[t] =
            make_ushort4(f2b(o0), f2b(o1), f2b(o2), f2b(o3));
    }
}

// ================= fp32 -> bf16 convert (n4 float4 groups)
__global__ void f2b_kernel(const float* __restrict__ in, unsigned short* __restrict__ out, int n4)
{
    int i = blockIdx.x * 256 + threadIdx.x;
    if (i >= n4) return;
    float4 v = ((const float4*)in)[i];
    ((ushort4*)out)[i] = make_ushort4(f2b(v.x), f2b(v.y), f2b(v.z), f2b(v.w));
}

// ================= memory(fp32) -> catb(bf16) rows [b*1536 + 0..1023]
__global__ void mem2catb_kernel(const float* __restrict__ mem, unsigned short* __restrict__ catb)
{
    int f = blockIdx.x * blockDim.x + threadIdx.x;
    const int total = BB * TTM * DM / 4;
    if (f >= total) return;
    const int per_b = TTM * DM / 4;
    int b = f / per_b, rem = f - b * per_b;
    float4 v = ((const float4*)mem)[f];
    ((ushort4*)catb)[(size_t)b * (LCAT * DM / 4) + rem] =
        make_ushort4(f2b(v.x), f2b(v.y), f2b(v.z), f2b(v.w));
}

static void run_scan(const float* dlt, const float* xc, const float* xdbl,
                     const unsigned short* xzb, const float* A_log, const float* Dv,
                     float* part_h, float* part_s, unsigned short* out, int L,
                     hipStream_t stream)
{
    int CH = L / NC;
    int blocks = BB * NC * (DI / 256);
    scan_part1<<<blocks, 256, 0, stream>>>(dlt, xc, xdbl, A_log, part_h, part_s, L, CH);
    scan_combine<<<BB * DI / 256, 256, 0, stream>>>(A_log, part_h, part_s);
    scan_part2<<<blocks, 256, 0, stream>>>(dlt, xc, xdbl, xzb, A_log, Dv, part_h, out, L, CH);
}

extern "C" void kernel_launch(void* const* d_in, const int* in_sizes, int n_in,
                              void* d_out, int out_size, void* d_ws, size_t ws_size,
                              hipStream_t stream)
{
    const float* tgt       = (const float*)d_in[0];
    const float* memory    = (const float*)d_in[1];
    const float* s_in_w    = (const float*)d_in[2];
    const float* s_conv_w  = (const float*)d_in[3];
    const float* s_conv_b  = (const float*)d_in[4];
    const float* s_xproj_w = (const float*)d_in[5];
    const float* s_dt_w    = (const float*)d_in[6];
    const float* s_dt_b    = (const float*)d_in[7];
    const float* s_A_log   = (const float*)d_in[8];
    const float* s_D_vec   = (const float*)d_in[9];
    const float* s_out_w   = (const float*)d_in[10];
    const float* c_in_w    = (const float*)d_in[11];
    const float* c_conv_w  = (const float*)d_in[12];
    const float* c_conv_b  = (const float*)d_in[13];
    const float* c_xproj_w = (const float*)d_in[14];
    const float* c_dt_w    = (const float*)d_in[15];
    const float* c_dt_b    = (const float*)d_in[16];
    const float* c_A_log   = (const float*)d_in[17];
    const float* c_D_vec   = (const float*)d_in[18];
    const float* c_out_w   = (const float*)d_in[19];
    const float* ln1_g     = (const float*)d_in[20];
    const float* ln1_b     = (const float*)d_in[21];
    const float* ln2_g     = (const float*)d_in[22];
    const float* ln2_b     = (const float*)d_in[23];
    const float* ln3_g     = (const float*)d_in[24];
    const float* ln3_b     = (const float*)d_in[25];
    const float* ffn_w1    = (const float*)d_in[26];
    const float* ffn_b1    = (const float*)d_in[27];
    const float* ffn_w2    = (const float*)d_in[28];
    const float* ffn_b2    = (const float*)d_in[29];
    float* outp = (float*)d_out;

    // ---- workspace layout ----
    // fp32 region (floats): 36,700,160 floats = 146.8 MB
    float* ws     = (float*)d_ws;
    float* xc     = ws;                     // 12582912  (also ffnout alias)
    float* xdbl   = xc     + 12582912;      // 786432
    float* dlt    = xdbl   + 786432;        // 12582912
    float* proj   = dlt    + 12582912;      // 2097152
    float* t1     = proj   + 2097152;       // 2097152
    float* tbuf   = t1     + 2097152;       // 2097152
    float* part_h = tbuf   + 2097152;       // 4194304
    float* part_s = part_h + 4194304;       // 262144
    float* ffnout = xc;                     // alias (xc dead after cross scan)
    // bf16 region (ushorts): 52,428,800 elems = 104.9 MB ; total 251.7 MB
    unsigned short* ub      = (unsigned short*)(part_s + 262144);
    unsigned short* catb    = ub;                   // 6291456
    unsigned short* tgtb    = catb    + 6291456;    // 2097152
    unsigned short* xzb     = tgtb    + 2097152;    // 25165824 (also fbuf alias)
    unsigned short* ygb     = xzb     + 25165824;   // 12582912
    unsigned short* tbbf    = ygb     + 12582912;   // 2097152
    unsigned short* s_in_wb = tbbf    + 2097152;    // 1048576
    unsigned short* c_in_wb = s_in_wb + 1048576;    // 1048576
    unsigned short* s_out_wb= c_in_wb + 1048576;    // 524288
    unsigned short* c_out_wb= s_out_wb+ 524288;     // 524288
    unsigned short* w1b     = c_out_wb+ 524288;     // 1048576
    unsigned short* w2b     = w1b     + 1048576;    // 1048576
    unsigned short* fbuf    = xzb;                  // FFN hidden alias

    // ---- converts ----
    f2b_kernel<<<(2097152/4 + 255)/256, 256, 0, stream>>>(tgt, tgtb, 2097152/4);
    mem2catb_kernel<<<(BB*TTM*DM/4 + 255)/256, 256, 0, stream>>>(memory, catb);
    f2b_kernel<<<(1048576/4 + 255)/256, 256, 0, stream>>>(s_in_w,  s_in_wb,  1048576/4);
    f2b_kernel<<<(1048576/4 + 255)/256, 256, 0, stream>>>(c_in_w,  c_in_wb,  1048576/4);
    f2b_kernel<<<(524288/4  + 255)/256, 256, 0, stream>>>(s_out_w, s_out_wb, 524288/4);
    f2b_kernel<<<(524288/4  + 255)/256, 256, 0, stream>>>(c_out_w, c_out_wb, 524288/4);
    f2b_kernel<<<(1048576/4 + 255)/256, 256, 0, stream>>>(ffn_w1,  w1b,      1048576/4);
    f2b_kernel<<<(1048576/4 + 255)/256, 256, 0, stream>>>(ffn_w2,  w2b,      1048576/4);

    // ---- self mamba (L=512, M=4096) ----
    mgemm_kernel<<<dim3(2048/128, 4096/128), 256, 0, stream>>>(
        tgtb, 4096, 0, 0, s_in_wb, nullptr, nullptr, xzb, 2048, 512, ACT_NONE);
    conv_silu_kernel<<<(BB*SS*DI + 255)/256, 256, 0, stream>>>(xzb, s_conv_w, s_conv_b, xc, SS, BB*SS*DI);
    gemm_kernel<<<dim3(1, 4096/64), 256, 0, stream>>>(
        xc, DI, 4096, 0, 0, s_xproj_w, nullptr, xdbl, 4096, 64, 1024, ACT_NONE);
    gemm_kernel<<<dim3(1024/64, 4096/64), 256, 0, stream>>>(
        xdbl, 64, 4096, 0, 0, s_dt_w, s_dt_b, dlt, 4096, 1024, 32, ACT_SOFTPLUS);
    run_scan(dlt, xc, xdbl, xzb, s_A_log, s_D_vec, part_h, part_s, ygb, SS, stream);
    mgemm_kernel<<<dim3(512/128, 4096/128), 256, 0, stream>>>(
        ygb, 4096, 0, 0, s_out_wb, nullptr, proj, nullptr, 512, 1024, ACT_NONE);
    // t = LN(tgt + proj): fp32 -> t1, bf16 -> catb rows [b*1536+1024+l]
    addln_kernel<<<4096, 128, 0, stream>>>(
        tgt, 4096, 0, 0, DM, proj, ln1_g, ln1_b,
        t1, 4096, 0, 0, DM, catb, 512, 1536, 1024, DM);

    // ---- cross mamba (L=1536, M=12288) ----
    mgemm_kernel<<<dim3(2048/128, 12288/128), 256, 0, stream>>>(
        catb, 12288, 0, 0, c_in_wb, nullptr, nullptr, xzb, 2048, 512, ACT_NONE);
    conv_silu_kernel<<<(BB*LCAT*DI + 255)/256, 256, 0, stream>>>(xzb, c_conv_w, c_conv_b, xc, LCAT, BB*LCAT*DI);
    gemm_kernel<<<dim3(1, 12288/64), 256, 0, stream>>>(
        xc, DI, 12288, 0, 0, c_xproj_w, nullptr, xdbl, 12288, 64, 1024, ACT_NONE);
    gemm_kernel<<<dim3(1024/64, 12288/64), 256, 0, stream>>>(
        xdbl, 64, 12288, 0, 0, c_dt_w, c_dt_b, dlt, 12288, 1024, 32, ACT_SOFTPLUS);
    run_scan(dlt, xc, xdbl, xzb, c_A_log, c_D_vec, part_h, part_s, ygb, LCAT, stream);
    // out proj over last S rows per batch: row(m) = (m/512)*1536 + 1024 + m%512
    mgemm_kernel<<<dim3(512/128, 4096/128), 256, 0, stream>>>(
        ygb, 512, 1536, 1024, c_out_wb, nullptr, proj, nullptr, 512, 1024, ACT_NONE);
    addln_kernel<<<4096, 128, 0, stream>>>(
        t1, 4096, 0, 0, DM, proj, ln2_g, ln2_b,
        tbuf, 4096, 0, 0, DM, tbbf, 4096, 0, 0, DM);

    // ---- FFN ----
    mgemm_kernel<<<dim3(2048/128, 4096/128), 256, 0, stream>>>(
        tbbf, 4096, 0, 0, w1b, ffn_b1, nullptr, fbuf, 2048, 512, ACT_RELU);
    mgemm_kernel<<<dim3(512/128, 4096/128), 256, 0, stream>>>(
        fbuf, 4096, 0, 0, w2b, ffn_b2, ffnout, nullptr, 512, 2048, ACT_NONE);
    addln_kernel<<<4096, 128, 0, stream>>>(
        tbuf, 4096, 0, 0, DM, ffnout, ln3_g, ln3_b,
        outp, 4096, 0, 0, DM, nullptr, 0, 0, 0, 0);
}

// Round 4
// 811.477 us; speedup vs baseline: 2.8840x; 1.0406x over previous
//
#include <hip/hip_runtime.h>
#include <math.h>

// Problem constants
#define DM    512
#define DI    1024
#define DSN   16
#define DTR   32
#define DFFN  2048
#define BB    8
#define SS    512
#define TTM   1024
#define LCAT  1536
#define NC    32      // scan chunks per sequence

#define ACT_NONE     0
#define ACT_RELU     1
#define ACT_DELTA    3   // split epilogue: n<1024 softplus+bias -> Cf(delta); 1024<=n<1056 -> C2(bc)

typedef __attribute__((ext_vector_type(8))) short short8;
typedef __attribute__((ext_vector_type(4))) float f32x4;

__device__ __forceinline__ unsigned short f2b(float f) {
    unsigned int u = __float_as_uint(f);
    return (unsigned short)((u + 0x7FFFu + ((u >> 16) & 1u)) >> 16);
}
__device__ __forceinline__ float b2f(unsigned short h) {
    return __uint_as_float(((unsigned int)h) << 16);
}
__device__ __forceinline__ void gld16(const void* g, void* l) {
    __builtin_amdgcn_global_load_lds(
        (const __attribute__((address_space(1))) void*)g,
        (__attribute__((address_space(3))) void*)l, 16, 0, 0);
}

__device__ __forceinline__ int map_row(int m, int mb, int bs, int ro) {
    int q = m / mb;
    return q * bs + ro + (m - q * mb);
}

// ================= bf16 MFMA GEMM: C[m,n] = act(A[row(m),k] * W[n,k] + bias[n])
// A: bf16, row stride K. W: bf16, N x K row-major. Tile 128x128, BK=32.
__global__ __launch_bounds__(256) void mgemm_kernel(
    const unsigned short* __restrict__ A, int mb, int bs, int ro,
    const unsigned short* __restrict__ W, const float* __restrict__ bias,
    float* __restrict__ Cf, unsigned short* __restrict__ Cb,
    float* __restrict__ C2,
    int N, int K, int act)
{
    __shared__ __align__(16) unsigned short As[128 * 32];
    __shared__ __align__(16) unsigned short Bs[128 * 32];
    int tid = threadIdx.x;
    int lane = tid & 63, wave = tid >> 6;
    int wy = wave >> 1, wx = wave & 1;
    int m0 = blockIdx.y * 128, n0 = blockIdx.x * 128;

    int sr = lane >> 2;
    int sc = (lane & 3) * 8;
    const unsigned short* ga[2];
    const unsigned short* gb[2];
    unsigned short* la[2];
    unsigned short* lb[2];
    #pragma unroll
    for (int j = 0; j < 2; j++) {
        int r = wave * 32 + j * 16 + sr;
        int gr = map_row(m0 + r, mb, bs, ro);
        ga[j] = A + (size_t)gr * K + sc;
        gb[j] = W + (size_t)(n0 + wave * 32 + j * 16 + sr) * K + sc;
        la[j] = As + (wave * 32 + j * 16) * 32;
        lb[j] = Bs + (wave * 32 + j * 16) * 32;
    }
    int fm = lane & 15;
    int fk = (lane >> 4) * 8;
    const unsigned short* arp = As + (wy * 64 + fm) * 32 + fk;
    const unsigned short* brp = Bs + (wx * 64 + fm) * 32 + fk;

    f32x4 acc[4][4];
    #pragma unroll
    for (int i = 0; i < 4; i++)
        #pragma unroll
        for (int j = 0; j < 4; j++) acc[i][j] = 0.f;

    for (int k0 = 0; k0 < K; k0 += 32) {
        #pragma unroll
        for (int j = 0; j < 2; j++) {
            gld16(ga[j] + k0, la[j]);
            gld16(gb[j] + k0, lb[j]);
        }
        __syncthreads();
        short8 af[4], bfr[4];
        #pragma unroll
        for (int t = 0; t < 4; t++) af[t]  = *(const short8*)(arp + t * 16 * 32);
        #pragma unroll
        for (int t = 0; t < 4; t++) bfr[t] = *(const short8*)(brp + t * 16 * 32);
        #pragma unroll
        for (int i = 0; i < 4; i++)
            #pragma unroll
            for (int j = 0; j < 4; j++)
                acc[i][j] = __builtin_amdgcn_mfma_f32_16x16x32_bf16(af[i], bfr[j], acc[i][j], 0, 0, 0);
        __syncthreads();
    }

    // epilogue: C/D layout col=lane&15 (n), row=(lane>>4)*4+reg (m)
    int en = lane & 15, em = (lane >> 4) * 4;
    if (act == ACT_DELTA) {
        #pragma unroll
        for (int j = 0; j < 4; j++) {
            int n = n0 + wx * 64 + j * 16 + en;
            bool is_delta = (n < 1024);
            if (!is_delta && n >= 1056) continue;
            float bv = is_delta ? bias[n] : 0.f;
            #pragma unroll
            for (int i = 0; i < 4; i++) {
                int mbase = m0 + wy * 64 + i * 16 + em;
                #pragma unroll
                for (int r = 0; r < 4; r++) {
                    float v = acc[i][j][r] + bv;
                    if (is_delta) {
                        v = (v > 20.f) ? v : log1pf(__expf(v));
                        Cf[(size_t)(mbase + r) * 1024 + n] = v;
                    } else {
                        C2[(size_t)(mbase + r) * 32 + (n - 1024)] = v;
                    }
                }
            }
        }
        return;
    }
    #pragma unroll
    for (int j = 0; j < 4; j++) {
        int n = n0 + wx * 64 + j * 16 + en;
        float bv = bias ? bias[n] : 0.f;
        #pragma unroll
        for (int i = 0; i < 4; i++) {
            int mbase = m0 + wy * 64 + i * 16 + em;
            #pragma unroll
            for (int r = 0; r < 4; r++) {
                float v = acc[i][j][r] + bv;
                if (act == ACT_RELU) v = v > 0.f ? v : 0.f;
                size_t off = (size_t)(mbase + r) * N + n;
                if (Cb) Cb[off] = f2b(v);
                else    Cf[off] = v;
            }
        }
    }
}

// ================= Wcomb fill: rows 0..1023 = dt_w @ xproj[:32]; 1024..1055 = xproj rows 32..63; rest 0
__global__ void wcomb_kernel(const float* __restrict__ dt_w,
                             const float* __restrict__ xproj,
                             unsigned short* __restrict__ out)
{
    int idx = blockIdx.x * 256 + threadIdx.x;   // n*1024 + k, n < 1152
    int n = idx >> 10, k = idx & 1023;
    float v = 0.f;
    if (n < 1024) {
        #pragma unroll
        for (int r = 0; r < DTR; r++)
            v = fmaf(dt_w[n * DTR + r], xproj[r * 1024 + k], v);
    } else if (n < 1056) {
        v = xproj[(n - 1024 + 32) * 1024 + k];
    }
    out[idx] = f2b(v);
}

// ================= Depthwise causal conv (width 4) + bias + SiLU. bf16 in, bf16 out.
__global__ void conv_silu_kernel(const unsigned short* __restrict__ xz,
                                 const float* __restrict__ cw,
                                 const float* __restrict__ cb,
                                 unsigned short* __restrict__ xc, int L, int total)
{
    int idx = blockIdx.x * blockDim.x + threadIdx.x;
    if (idx >= total) return;
    int d = idx & (DI - 1);
    int r = idx >> 10;     // b*L + l
    int l = r % L;
    float acc = cb[d];
    #pragma unroll
    for (int k = 0; k < 4; k++) {
        int ls = l - 3 + k;
        if (ls >= 0) acc = fmaf(b2f(xz[(size_t)(r - 3 + k) * 2048 + d]), cw[d * 4 + k], acc);
    }
    float s = acc / (1.f + __expf(-acc));
    xc[idx] = f2b(s);
}

// ================= Chunked selective scan
__global__ __launch_bounds__(256) void scan_part1(
    const float* __restrict__ delta, const unsigned short* __restrict__ xc,
    const float* __restrict__ bc, const float* __restrict__ A_log,
    float* __restrict__ part_h, float* __restrict__ part_s, int L, int CH)
{
    int tid = threadIdx.x;
    int dblk = blockIdx.x & 3;
    int c    = (blockIdx.x >> 2) & (NC - 1);
    int b    = blockIdx.x >> 7;
    int d    = dblk * 256 + tid;
    float A[DSN];
    #pragma unroll
    for (int s = 0; s < DSN; s++) A[s] = -__expf(A_log[d * DSN + s]);
    float h[DSN];
    #pragma unroll
    for (int s = 0; s < DSN; s++) h[s] = 0.f;
    float ssum = 0.f;
    int l0 = c * CH;
    for (int l = l0; l < l0 + CH; l++) {
        size_t r = (size_t)b * L + l;
        float4 bq[4];
        const float4* bp = (const float4*)(bc + r * 32);
        #pragma unroll
        for (int q = 0; q < 4; q++) bq[q] = bp[q];
        const float* Bm = (const float*)&bq[0];
        float dl = delta[r * DI + d];
        float u  = b2f(xc[r * DI + d]);
        float du = dl * u;
        ssum += dl;
        #pragma unroll
        for (int s = 0; s < DSN; s++)
            h[s] = fmaf(__expf(dl * A[s]), h[s], du * Bm[s]);
    }
    size_t base = ((size_t)(b * NC + c) * DI + d) * DSN;
    #pragma unroll
    for (int q = 0; q < 4; q++)
        ((float4*)(part_h + base))[q] = make_float4(h[q*4], h[q*4+1], h[q*4+2], h[q*4+3]);
    part_s[(size_t)(b * NC + c) * DI + d] = ssum;
}

__global__ __launch_bounds__(256) void scan_combine(
    const float* __restrict__ A_log,
    float* __restrict__ part_h, const float* __restrict__ part_s)
{
    int idx = blockIdx.x * 256 + threadIdx.x;
    int b = idx >> 10, d = idx & (DI - 1);
    float A[DSN];
    #pragma unroll
    for (int s = 0; s < DSN; s++) A[s] = -__expf(A_log[d * DSN + s]);
    float h[DSN];
    #pragma unroll
    for (int s = 0; s < DSN; s++) h[s] = 0.f;
    for (int c = 0; c < NC; c++) {
        size_t base = ((size_t)(b * NC + c) * DI + d) * DSN;
        float4 ph4[4];
        #pragma unroll
        for (int q = 0; q < 4; q++) ph4[q] = ((const float4*)(part_h + base))[q];
        const float* ph = (const float*)&ph4[0];
        float S = part_s[(size_t)(b * NC + c) * DI + d];
        #pragma unroll
        for (int q = 0; q < 4; q++)
            ((float4*)(part_h + base))[q] = make_float4(h[q*4], h[q*4+1], h[q*4+2], h[q*4+3]);
        #pragma unroll
        for (int s = 0; s < DSN; s++)
            h[s] = fmaf(__expf(A[s] * S), h[s], ph[s]);
    }
}

// pass 3: rescan chunk from h_in, emit gated output to bf16 buffer.
__global__ __launch_bounds__(256) void scan_part2(
    const float* __restrict__ delta, const unsigned short* __restrict__ xc,
    const float* __restrict__ bc, const unsigned short* __restrict__ xz,
    const float* __restrict__ A_log, const float* __restrict__ Dv,
    const float* __restrict__ part_h,
    unsigned short* __restrict__ out, int L, int CH)
{
    int tid = threadIdx.x;
    int dblk = blockIdx.x & 3;
    int c    = (blockIdx.x >> 2) & (NC - 1);
    int b    = blockIdx.x >> 7;
    int d    = dblk * 256 + tid;
    float A[DSN];
    #pragma unroll
    for (int s = 0; s < DSN; s++) A[s] = -__expf(A_log[d * DSN + s]);
    float Dvd = Dv[d];
    size_t base = ((size_t)(b * NC + c) * DI + d) * DSN;
    float h4[4][4];
    #pragma unroll
    for (int q = 0; q < 4; q++) *((float4*)h4[q]) = ((const float4*)(part_h + base))[q];
    float h[DSN];
    #pragma unroll
    for (int s = 0; s < DSN; s++) h[s] = h4[s >> 2][s & 3];
    int l0 = c * CH;
    for (int l = l0; l < l0 + CH; l++) {
        size_t r = (size_t)b * L + l;
        float4 bq[8];
        const float4* bp = (const float4*)(bc + r * 32);
        #pragma unroll
        for (int q = 0; q < 8; q++) bq[q] = bp[q];
        const float* Bm = (const float*)&bq[0];
        const float* Cm = Bm + DSN;
        float dl = delta[r * DI + d];
        float u  = b2f(xc[r * DI + d]);
        float du = dl * u;
        float y = 0.f;
        #pragma unroll
        for (int s = 0; s < DSN; s++) {
            h[s] = fmaf(__expf(dl * A[s]), h[s], du * Bm[s]);
            y = fmaf(h[s], Cm[s], y);
        }
        float z = b2f(xz[r * 2048 + DI + d]);
        float sil = z / (1.f + __expf(-z));
        out[r * DI + d] = f2b((y + u * Dvd) * sil);
    }
}

// ================= residual add + LayerNorm; optional fp32 and bf16 outputs
__global__ __launch_bounds__(128) void addln_kernel(
    const float* __restrict__ a, int amb, int absd, int aro, int lda,
    const float* __restrict__ bsrc,
    const float* __restrict__ g, const float* __restrict__ be,
    float* __restrict__ outf, int omb, int obsd, int oro, int ldo,
    unsigned short* __restrict__ outb, int bmb, int bbsd, int bro, int ldb)
{
    int m = blockIdx.x, t = threadIdx.x;
    int ar = map_row(m, amb, absd, aro);
    float4 x4 = ((const float4*)(a + (size_t)ar * lda))[t];
    float4 y4 = ((const float4*)(bsrc + (size_t)m * DM))[t];
    float v[4] = {x4.x + y4.x, x4.y + y4.y, x4.z + y4.z, x4.w + y4.w};
    float sum = v[0] + v[1] + v[2] + v[3];
    float sq  = v[0]*v[0] + v[1]*v[1] + v[2]*v[2] + v[3]*v[3];
    #pragma unroll
    for (int o = 32; o > 0; o >>= 1) {
        sum += __shfl_down(sum, o);
        sq  += __shfl_down(sq, o);
    }
    __shared__ float s0[2], s1[2];
    if ((t & 63) == 0) { s0[t >> 6] = sum; s1[t >> 6] = sq; }
    __syncthreads();
    float tot = s0[0] + s0[1];
    float tsq = s1[0] + s1[1];
    float mu = tot * (1.f / DM);
    float var = tsq * (1.f / DM) - mu * mu;
    float rs = rsqrtf(var + 1e-6f);
    float4 g4 = ((const float4*)g)[t];
    float4 b4 = ((const float4*)be)[t];
    float o0 = (v[0] - mu) * rs * g4.x + b4.x;
    float o1 = (v[1] - mu) * rs * g4.y + b4.y;
    float o2 = (v[2] - mu) * rs * g4.z + b4.z;
    float o3 = (v[3] - mu) * rs * g4.w + b4.w;
    if (outf) {
        int orow = map_row(m, omb, obsd, oro);
        ((float4*)(outf + (size_t)orow * ldo))[t] = make_float4(o0, o1, o2, o3);
    }
    if (outb) {
        int brow = map_row(m, bmb, bbsd, bro);
        ((ushort4*)(outb + (size_t)brow * ldb))[t] =
            make_ushort4(f2b(o0), f2b(o1), f2b(o2), f2b(o3));
    }
}

// ================= fp32 -> bf16 convert (n4 float4 groups)
__global__ void f2b_kernel(const float* __restrict__ in, unsigned short* __restrict__ out, int n4)
{
    int i = blockIdx.x * 256 + threadIdx.x;
    if (i >= n4) return;
    float4 v = ((const float4*)in)[i];
    ((ushort4*)out)[i] = make_ushort4(f2b(v.x), f2b(v.y), f2b(v.z), f2b(v.w));
}

// ================= merged 6-weight fp32 -> bf16 convert (contiguous bf16 output region)
struct W6 { const float* p[6]; };
// cumulative float4 boundaries: s_in, c_in, s_out, c_out, w1, w2
__global__ void wconv_kernel(W6 w, unsigned short* __restrict__ out)
{
    const int cum[7] = {0, 262144, 524288, 655360, 786432, 1048576, 1310720};
    int i = blockIdx.x * 256 + threadIdx.x;
    if (i >= 1310720) return;
    int seg = 0;
    #pragma unroll
    for (int s = 1; s < 6; s++) seg += (i >= cum[s]);
    float4 v = ((const float4*)w.p[seg])[i - cum[seg]];
    ((ushort4*)out)[i] = make_ushort4(f2b(v.x), f2b(v.y), f2b(v.z), f2b(v.w));
}

// ================= memory(fp32) -> catb(bf16) rows [b*1536 + 0..1023]
__global__ void mem2catb_kernel(const float* __restrict__ mem, unsigned short* __restrict__ catb)
{
    int f = blockIdx.x * blockDim.x + threadIdx.x;
    const int total = BB * TTM * DM / 4;
    if (f >= total) return;
    const int per_b = TTM * DM / 4;
    int b = f / per_b, rem = f - b * per_b;
    float4 v = ((const float4*)mem)[f];
    ((ushort4*)catb)[(size_t)b * (LCAT * DM / 4) + rem] =
        make_ushort4(f2b(v.x), f2b(v.y), f2b(v.z), f2b(v.w));
}

static void run_scan(const float* dlt, const unsigned short* xcb, const float* bc,
                     const unsigned short* xzb, const float* A_log, const float* Dv,
                     float* part_h, float* part_s, unsigned short* out, int L,
                     hipStream_t stream)
{
    int CH = L / NC;
    int blocks = BB * NC * (DI / 256);
    scan_part1<<<blocks, 256, 0, stream>>>(dlt, xcb, bc, A_log, part_h, part_s, L, CH);
    scan_combine<<<BB * DI / 256, 256, 0, stream>>>(A_log, part_h, part_s);
    scan_part2<<<blocks, 256, 0, stream>>>(dlt, xcb, bc, xzb, A_log, Dv, part_h, out, L, CH);
}

extern "C" void kernel_launch(void* const* d_in, const int* in_sizes, int n_in,
                              void* d_out, int out_size, void* d_ws, size_t ws_size,
                              hipStream_t stream)
{
    const float* tgt       = (const float*)d_in[0];
    const float* memory    = (const float*)d_in[1];
    const float* s_in_w    = (const float*)d_in[2];
    const float* s_conv_w  = (const float*)d_in[3];
    const float* s_conv_b  = (const float*)d_in[4];
    const float* s_xproj_w = (const float*)d_in[5];
    const float* s_dt_w    = (const float*)d_in[6];
    const float* s_dt_b    = (const float*)d_in[7];
    const float* s_A_log   = (const float*)d_in[8];
    const float* s_D_vec   = (const float*)d_in[9];
    const float* s_out_w   = (const float*)d_in[10];
    const float* c_in_w    = (const float*)d_in[11];
    const float* c_conv_w  = (const float*)d_in[12];
    const float* c_conv_b  = (const float*)d_in[13];
    const float* c_xproj_w = (const float*)d_in[14];
    const float* c_dt_w    = (const float*)d_in[15];
    const float* c_dt_b    = (const float*)d_in[16];
    const float* c_A_log   = (const float*)d_in[17];
    const float* c_D_vec   = (const float*)d_in[18];
    const float* c_out_w   = (const float*)d_in[19];
    const float* ln1_g     = (const float*)d_in[20];
    const float* ln1_b     = (const float*)d_in[21];
    const float* ln2_g     = (const float*)d_in[22];
    const float* ln2_b     = (const float*)d_in[23];
    const float* ln3_g     = (const float*)d_in[24];
    const float* ln3_b     = (const float*)d_in[25];
    const float* ffn_w1    = (const float*)d_in[26];
    const float* ffn_b1    = (const float*)d_in[27];
    const float* ffn_w2    = (const float*)d_in[28];
    const float* ffn_b2    = (const float*)d_in[29];
    float* outp = (float*)d_out;

    // ---- workspace layout ----
    // fp32 region (floats): 23,723,008 floats = 94.9 MB
    float* ws     = (float*)d_ws;
    float* dlt    = ws;                     // 12582912 (delta, fp32; ffnout aliases)
    float* bc     = dlt    + 12582912;      // 393216  (12288 x 32: B|C)
    float* proj   = bc     + 393216;        // 2097152
    float* t1     = proj   + 2097152;       // 2097152
    float* tbuf   = t1     + 2097152;       // 2097152
    float* part_h = tbuf   + 2097152;       // 4194304
    float* part_s = part_h + 4194304;       // 262144
    float* ffnout = dlt;                    // alias (dlt dead after cross scan)
    // bf16 region (ushorts): 68,419,584 elems = 136.8 MB ; total 231.7 MB
    unsigned short* ub      = (unsigned short*)(part_s + 262144);
    unsigned short* catb    = ub;                   // 6291456
    unsigned short* tgtb    = catb    + 6291456;    // 2097152
    unsigned short* xzb     = tgtb    + 2097152;    // 25165824 (also fbuf alias)
    unsigned short* xcb     = xzb     + 25165824;   // 12582912
    unsigned short* ygb     = xcb     + 12582912;   // 12582912
    unsigned short* tbbf    = ygb     + 12582912;   // 2097152
    unsigned short* s_in_wb = tbbf    + 2097152;    // 1048576  (6-weight block, contiguous)
    unsigned short* c_in_wb = s_in_wb + 1048576;    // 1048576
    unsigned short* s_out_wb= c_in_wb + 1048576;    // 524288
    unsigned short* c_out_wb= s_out_wb+ 524288;     // 524288
    unsigned short* w1b     = c_out_wb+ 524288;     // 1048576
    unsigned short* w2b     = w1b     + 1048576;    // 1048576
    unsigned short* wcomb_s = w2b     + 1048576;    // 1179648 (1152 x 1024)
    unsigned short* wcomb_c = wcomb_s + 1179648;    // 1179648
    unsigned short* fbuf    = xzb;                  // FFN hidden alias

    // ---- converts & combined-weight fills ----
    f2b_kernel<<<(2097152/4 + 255)/256, 256, 0, stream>>>(tgt, tgtb, 2097152/4);
    mem2catb_kernel<<<(BB*TTM*DM/4 + 255)/256, 256, 0, stream>>>(memory, catb);
    {
        W6 w; w.p[0]=s_in_w; w.p[1]=c_in_w; w.p[2]=s_out_w; w.p[3]=c_out_w; w.p[4]=ffn_w1; w.p[5]=ffn_w2;
        wconv_kernel<<<(1310720 + 255)/256, 256, 0, stream>>>(w, s_in_wb);
    }
    wcomb_kernel<<<(1152*1024)/256, 256, 0, stream>>>(s_dt_w, s_xproj_w, wcomb_s);
    wcomb_kernel<<<(1152*1024)/256, 256, 0, stream>>>(c_dt_w, c_xproj_w, wcomb_c);

    // ---- self mamba (L=512, M=4096) ----
    mgemm_kernel<<<dim3(2048/128, 4096/128), 256, 0, stream>>>(
        tgtb, 4096, 0, 0, s_in_wb, nullptr, nullptr, xzb, nullptr, 2048, 512, ACT_NONE);
    conv_silu_kernel<<<(BB*SS*DI + 255)/256, 256, 0, stream>>>(xzb, s_conv_w, s_conv_b, xcb, SS, BB*SS*DI);
    // combined delta + BC GEMM: M=4096, Ncomb=1152, K=1024
    mgemm_kernel<<<dim3(1152/128, 4096/128), 256, 0, stream>>>(
        xcb, 4096, 0, 0, wcomb_s, s_dt_b, dlt, nullptr, bc, 1152, 1024, ACT_DELTA);
    run_scan(dlt, xcb, bc, xzb, s_A_log, s_D_vec, part_h, part_s, ygb, SS, stream);
    mgemm_kernel<<<dim3(512/128, 4096/128), 256, 0, stream>>>(
        ygb, 4096, 0, 0, s_out_wb, nullptr, proj, nullptr, nullptr, 512, 1024, ACT_NONE);
    // t = LN(tgt + proj): fp32 -> t1, bf16 -> catb rows [b*1536+1024+l]
    addln_kernel<<<4096, 128, 0, stream>>>(
        tgt, 4096, 0, 0, DM, proj, ln1_g, ln1_b,
        t1, 4096, 0, 0, DM, catb, 512, 1536, 1024, DM);

    // ---- cross mamba (L=1536, M=12288) ----
    mgemm_kernel<<<dim3(2048/128, 12288/128), 256, 0, stream>>>(
        catb, 12288, 0, 0, c_in_wb, nullptr, nullptr, xzb, nullptr, 2048, 512, ACT_NONE);
    conv_silu_kernel<<<(BB*LCAT*DI + 255)/256, 256, 0, stream>>>(xzb, c_conv_w, c_conv_b, xcb, LCAT, BB*LCAT*DI);
    mgemm_kernel<<<dim3(1152/128, 12288/128), 256, 0, stream>>>(
        xcb, 12288, 0, 0, wcomb_c, c_dt_b, dlt, nullptr, bc, 1152, 1024, ACT_DELTA);
    run_scan(dlt, xcb, bc, xzb, c_A_log, c_D_vec, part_h, part_s, ygb, LCAT, stream);
    // out proj over last S rows per batch: row(m) = (m/512)*1536 + 1024 + m%512
    mgemm_kernel<<<dim3(512/128, 4096/128), 256, 0, stream>>>(
        ygb, 512, 1536, 1024, c_out_wb, nullptr, proj, nullptr, nullptr, 512, 1024, ACT_NONE);
    addln_kernel<<<4096, 128, 0, stream>>>(
        t1, 4096, 0, 0, DM, proj, ln2_g, ln2_b,
        tbuf, 4096, 0, 0, DM, tbbf, 4096, 0, 0, DM);

    // ---- FFN ----
    mgemm_kernel<<<dim3(2048/128, 4096/128), 256, 0, stream>>>(
        tbbf, 4096, 0, 0, w1b, ffn_b1, nullptr, fbuf, nullptr, 2048, 512, ACT_RELU);
    mgemm_kernel<<<dim3(512/128, 4096/128), 256, 0, stream>>>(
        fbuf, 4096, 0, 0, w2b, ffn_b2, ffnout, nullptr, nullptr, 512, 2048, ACT_NONE);
    addln_kernel<<<4096, 128, 0, stream>>>(
        tbuf, 4096, 0, 0, DM, ffnout, ln3_g, ln3_b,
        outp, 4096, 0, 0, DM, nullptr, 0, 0, 0, 0);
}

// Round 5
// 739.409 us; speedup vs baseline: 3.1651x; 1.0975x over previous
//
#include <hip/hip_runtime.h>
#include <math.h>

// Problem constants
#define DM    512
#define DI    1024
#define DSN   16
#define DTR   32
#define DFFN  2048
#define BB    8
#define SS    512
#define TTM   1024
#define LCAT  1536
#define NC    32      // scan chunks per sequence

#define ACT_NONE     0
#define ACT_RELU     1
#define ACT_DELTA    3   // split epilogue: n<1024 softplus+bias -> Cb(delta bf16); 1024<=n<1056 -> C2(bc fp32)

typedef __attribute__((ext_vector_type(8))) short short8;
typedef __attribute__((ext_vector_type(4))) float f32x4;

__device__ __forceinline__ unsigned short f2b(float f) {
    unsigned int u = __float_as_uint(f);
    return (unsigned short)((u + 0x7FFFu + ((u >> 16) & 1u)) >> 16);
}
__device__ __forceinline__ float b2f(unsigned short h) {
    return __uint_as_float(((unsigned int)h) << 16);
}
__device__ __forceinline__ float fast_softplus(float v) {
    return (v > 20.f) ? v : __logf(1.f + __expf(v));
}
__device__ __forceinline__ void gld16(const void* g, void* l) {
    __builtin_amdgcn_global_load_lds(
        (const __attribute__((address_space(1))) void*)g,
        (__attribute__((address_space(3))) void*)l, 16, 0, 0);
}

__device__ __forceinline__ int map_row(int m, int mb, int bs, int ro) {
    int q = m / mb;
    return q * bs + ro + (m - q * mb);
}

// ================= bf16 MFMA GEMM: C[m,n] = act(A[row(m),k] * W[n,k] + bias[n])
// A: bf16, row stride K. W: bf16, N x K row-major. Tile 128x128, BK=32.
// Block mapping: XCD-band swizzle — each XCD (blocks f%8) owns a contiguous
// band of m-tiles with ALL n-tiles, so the A-band stays resident in its L2.
__global__ __launch_bounds__(256) void mgemm_kernel(
    const unsigned short* __restrict__ A, int mb, int bs, int ro,
    const unsigned short* __restrict__ W, const float* __restrict__ bias,
    float* __restrict__ Cf, unsigned short* __restrict__ Cb,
    float* __restrict__ C2,
    int N, int K, int act)
{
    __shared__ __align__(16) unsigned short As[128 * 32];
    __shared__ __align__(16) unsigned short Bs[128 * 32];
    int tid = threadIdx.x;
    int lane = tid & 63, wave = tid >> 6;
    int wy = wave >> 1, wx = wave & 1;
    // XCD-band swizzle (gridDim.y assumed divisible by 8)
    int nx = gridDim.x;
    int f = blockIdx.y * nx + blockIdx.x;
    int xcd = f & 7, j2 = f >> 3;
    int bandh = gridDim.y >> 3;
    int m0 = (xcd * bandh + j2 / nx) * 128;
    int n0 = (j2 % nx) * 128;

    int sr = lane >> 2;
    int sc = (lane & 3) * 8;
    const unsigned short* ga[2];
    const unsigned short* gb[2];
    unsigned short* la[2];
    unsigned short* lb[2];
    #pragma unroll
    for (int j = 0; j < 2; j++) {
        int r = wave * 32 + j * 16 + sr;
        int gr = map_row(m0 + r, mb, bs, ro);
        ga[j] = A + (size_t)gr * K + sc;
        gb[j] = W + (size_t)(n0 + wave * 32 + j * 16 + sr) * K + sc;
        la[j] = As + (wave * 32 + j * 16) * 32;
        lb[j] = Bs + (wave * 32 + j * 16) * 32;
    }
    int fm = lane & 15;
    int fk = (lane >> 4) * 8;
    const unsigned short* arp = As + (wy * 64 + fm) * 32 + fk;
    const unsigned short* brp = Bs + (wx * 64 + fm) * 32 + fk;

    f32x4 acc[4][4];
    #pragma unroll
    for (int i = 0; i < 4; i++)
        #pragma unroll
        for (int j = 0; j < 4; j++) acc[i][j] = 0.f;

    for (int k0 = 0; k0 < K; k0 += 32) {
        #pragma unroll
        for (int j = 0; j < 2; j++) {
            gld16(ga[j] + k0, la[j]);
            gld16(gb[j] + k0, lb[j]);
        }
        __syncthreads();
        short8 af[4], bfr[4];
        #pragma unroll
        for (int t = 0; t < 4; t++) af[t]  = *(const short8*)(arp + t * 16 * 32);
        #pragma unroll
        for (int t = 0; t < 4; t++) bfr[t] = *(const short8*)(brp + t * 16 * 32);
        #pragma unroll
        for (int i = 0; i < 4; i++)
            #pragma unroll
            for (int j = 0; j < 4; j++)
                acc[i][j] = __builtin_amdgcn_mfma_f32_16x16x32_bf16(af[i], bfr[j], acc[i][j], 0, 0, 0);
        __syncthreads();
    }

    // epilogue: C/D layout col=lane&15 (n), row=(lane>>4)*4+reg (m)
    int en = lane & 15, em = (lane >> 4) * 4;
    if (act == ACT_DELTA) {
        #pragma unroll
        for (int j = 0; j < 4; j++) {
            int n = n0 + wx * 64 + j * 16 + en;
            bool is_delta = (n < 1024);
            if (!is_delta && n >= 1056) continue;
            float bv = is_delta ? bias[n] : 0.f;
            #pragma unroll
            for (int i = 0; i < 4; i++) {
                int mbase = m0 + wy * 64 + i * 16 + em;
                #pragma unroll
                for (int r = 0; r < 4; r++) {
                    float v = acc[i][j][r] + bv;
                    if (is_delta) {
                        Cb[(size_t)(mbase + r) * 1024 + n] = f2b(fast_softplus(v));
                    } else {
                        C2[(size_t)(mbase + r) * 32 + (n - 1024)] = v;
                    }
                }
            }
        }
        return;
    }
    #pragma unroll
    for (int j = 0; j < 4; j++) {
        int n = n0 + wx * 64 + j * 16 + en;
        float bv = bias ? bias[n] : 0.f;
        #pragma unroll
        for (int i = 0; i < 4; i++) {
            int mbase = m0 + wy * 64 + i * 16 + em;
            #pragma unroll
            for (int r = 0; r < 4; r++) {
                float v = acc[i][j][r] + bv;
                if (act == ACT_RELU) v = v > 0.f ? v : 0.f;
                size_t off = (size_t)(mbase + r) * N + n;
                if (Cb) Cb[off] = f2b(v);
                else    Cf[off] = v;
            }
        }
    }
}

// ================= Wcomb fill: rows 0..1023 = dt_w @ xproj[:32]; 1024..1055 = xproj rows 32..63; rest 0
__global__ void wcomb_kernel(const float* __restrict__ dt_w,
                             const float* __restrict__ xproj,
                             unsigned short* __restrict__ out)
{
    int idx = blockIdx.x * 256 + threadIdx.x;   // n*1024 + k, n < 1152
    int n = idx >> 10, k = idx & 1023;
    float v = 0.f;
    if (n < 1024) {
        #pragma unroll
        for (int r = 0; r < DTR; r++)
            v = fmaf(dt_w[n * DTR + r], xproj[r * 1024 + k], v);
    } else if (n < 1056) {
        v = xproj[(n - 1024 + 32) * 1024 + k];
    }
    out[idx] = f2b(v);
}

// ================= Depthwise causal conv (width 4) + bias + SiLU. bf16 in, bf16 out.
__global__ void conv_silu_kernel(const unsigned short* __restrict__ xz,
                                 const float* __restrict__ cw,
                                 const float* __restrict__ cb,
                                 unsigned short* __restrict__ xc, int L, int total)
{
    int idx = blockIdx.x * blockDim.x + threadIdx.x;
    if (idx >= total) return;
    int d = idx & (DI - 1);
    int r = idx >> 10;     // b*L + l
    int l = r % L;
    float acc = cb[d];
    #pragma unroll
    for (int k = 0; k < 4; k++) {
        int ls = l - 3 + k;
        if (ls >= 0) acc = fmaf(b2f(xz[(size_t)(r - 3 + k) * 2048 + d]), cw[d * 4 + k], acc);
    }
    float s = acc / (1.f + __expf(-acc));
    xc[idx] = f2b(s);
}

// ================= Chunked selective scan (delta now bf16)
__global__ __launch_bounds__(256) void scan_part1(
    const unsigned short* __restrict__ delta, const unsigned short* __restrict__ xc,
    const float* __restrict__ bc, const float* __restrict__ A_log,
    float* __restrict__ part_h, float* __restrict__ part_s, int L, int CH)
{
    int tid = threadIdx.x;
    int dblk = blockIdx.x & 3;
    int c    = (blockIdx.x >> 2) & (NC - 1);
    int b    = blockIdx.x >> 7;
    int d    = dblk * 256 + tid;
    float A[DSN];
    #pragma unroll
    for (int s = 0; s < DSN; s++) A[s] = -__expf(A_log[d * DSN + s]);
    float h[DSN];
    #pragma unroll
    for (int s = 0; s < DSN; s++) h[s] = 0.f;
    float ssum = 0.f;
    int l0 = c * CH;
    for (int l = l0; l < l0 + CH; l++) {
        size_t r = (size_t)b * L + l;
        float4 bq[4];
        const float4* bp = (const float4*)(bc + r * 32);
        #pragma unroll
        for (int q = 0; q < 4; q++) bq[q] = bp[q];
        const float* Bm = (const float*)&bq[0];
        float dl = b2f(delta[r * DI + d]);
        float u  = b2f(xc[r * DI + d]);
        float du = dl * u;
        ssum += dl;
        #pragma unroll
        for (int s = 0; s < DSN; s++)
            h[s] = fmaf(__expf(dl * A[s]), h[s], du * Bm[s]);
    }
    size_t base = ((size_t)(b * NC + c) * DI + d) * DSN;
    #pragma unroll
    for (int q = 0; q < 4; q++)
        ((float4*)(part_h + base))[q] = make_float4(h[q*4], h[q*4+1], h[q*4+2], h[q*4+3]);
    part_s[(size_t)(b * NC + c) * DI + d] = ssum;
}

__global__ __launch_bounds__(256) void scan_combine(
    const float* __restrict__ A_log,
    float* __restrict__ part_h, const float* __restrict__ part_s)
{
    int idx = blockIdx.x * 256 + threadIdx.x;
    int b = idx >> 10, d = idx & (DI - 1);
    float A[DSN];
    #pragma unroll
    for (int s = 0; s < DSN; s++) A[s] = -__expf(A_log[d * DSN + s]);
    float h[DSN];
    #pragma unroll
    for (int s = 0; s < DSN; s++) h[s] = 0.f;
    for (int c = 0; c < NC; c++) {
        size_t base = ((size_t)(b * NC + c) * DI + d) * DSN;
        float4 ph4[4];
        #pragma unroll
        for (int q = 0; q < 4; q++) ph4[q] = ((const float4*)(part_h + base))[q];
        const float* ph = (const float*)&ph4[0];
        float S = part_s[(size_t)(b * NC + c) * DI + d];
        #pragma unroll
        for (int q = 0; q < 4; q++)
            ((float4*)(part_h + base))[q] = make_float4(h[q*4], h[q*4+1], h[q*4+2], h[q*4+3]);
        #pragma unroll
        for (int s = 0; s < DSN; s++)
            h[s] = fmaf(__expf(A[s] * S), h[s], ph[s]);
    }
}

// pass 3: rescan chunk from h_in, emit gated output to bf16 buffer.
__global__ __launch_bounds__(256) void scan_part2(
    const unsigned short* __restrict__ delta, const unsigned short* __restrict__ xc,
    const float* __restrict__ bc, const unsigned short* __restrict__ xz,
    const float* __restrict__ A_log, const float* __restrict__ Dv,
    const float* __restrict__ part_h,
    unsigned short* __restrict__ out, int L, int CH)
{
    int tid = threadIdx.x;
    int dblk = blockIdx.x & 3;
    int c    = (blockIdx.x >> 2) & (NC - 1);
    int b    = blockIdx.x >> 7;
    int d    = dblk * 256 + tid;
    float A[DSN];
    #pragma unroll
    for (int s = 0; s < DSN; s++) A[s] = -__expf(A_log[d * DSN + s]);
    float Dvd = Dv[d];
    size_t base = ((size_t)(b * NC + c) * DI + d) * DSN;
    float h4[4][4];
    #pragma unroll
    for (int q = 0; q < 4; q++) *((float4*)h4[q]) = ((const float4*)(part_h + base))[q];
    float h[DSN];
    #pragma unroll
    for (int s = 0; s < DSN; s++) h[s] = h4[s >> 2][s & 3];
    int l0 = c * CH;
    for (int l = l0; l < l0 + CH; l++) {
        size_t r = (size_t)b * L + l;
        float4 bq[8];
        const float4* bp = (const float4*)(bc + r * 32);
        #pragma unroll
        for (int q = 0; q < 8; q++) bq[q] = bp[q];
        const float* Bm = (const float*)&bq[0];
        const float* Cm = Bm + DSN;
        float dl = b2f(delta[r * DI + d]);
        float u  = b2f(xc[r * DI + d]);
        float du = dl * u;
        float y = 0.f;
        #pragma unroll
        for (int s = 0; s < DSN; s++) {
            h[s] = fmaf(__expf(dl * A[s]), h[s], du * Bm[s]);
            y = fmaf(h[s], Cm[s], y);
        }
        float z = b2f(xz[r * 2048 + DI + d]);
        float sil = z / (1.f + __expf(-z));
        out[r * DI + d] = f2b((y + u * Dvd) * sil);
    }
}

// ================= residual add + LayerNorm; optional fp32 and bf16 outputs
__global__ __launch_bounds__(128) void addln_kernel(
    const float* __restrict__ a, int amb, int absd, int aro, int lda,
    const float* __restrict__ bsrc,
    const float* __restrict__ g, const float* __restrict__ be,
    float* __restrict__ outf, int omb, int obsd, int oro, int ldo,
    unsigned short* __restrict__ outb, int bmb, int bbsd, int bro, int ldb)
{
    int m = blockIdx.x, t = threadIdx.x;
    int ar = map_row(m, amb, absd, aro);
    float4 x4 = ((const float4*)(a + (size_t)ar * lda))[t];
    float4 y4 = ((const float4*)(bsrc + (size_t)m * DM))[t];
    float v[4] = {x4.x + y4.x, x4.y + y4.y, x4.z + y4.z, x4.w + y4.w};
    float sum = v[0] + v[1] + v[2] + v[3];
    float sq  = v[0]*v[0] + v[1]*v[1] + v[2]*v[2] + v[3]*v[3];
    #pragma unroll
    for (int o = 32; o > 0; o >>= 1) {
        sum += __shfl_down(sum, o);
        sq  += __shfl_down(sq, o);
    }
    __shared__ float s0[2], s1[2];
    if ((t & 63) == 0) { s0[t >> 6] = sum; s1[t >> 6] = sq; }
    __syncthreads();
    float tot = s0[0] + s0[1];
    float tsq = s1[0] + s1[1];
    float mu = tot * (1.f / DM);
    float var = tsq * (1.f / DM) - mu * mu;
    float rs = rsqrtf(var + 1e-6f);
    float4 g4 = ((const float4*)g)[t];
    float4 b4 = ((const float4*)be)[t];
    float o0 = (v[0] - mu) * rs * g4.x + b4.x;
    float o1 = (v[1] - mu) * rs * g4.y + b4.y;
    float o2 = (v[2] - mu) * rs * g4.z + b4.z;
    float o3 = (v[3] - mu) * rs * g4.w + b4.w;
    if (outf) {
        int orow = map_row(m, omb, obsd, oro);
        ((float4*)(outf + (size_t)orow * ldo))[t] = make_float4(o0, o1, o2, o3);
    }
    if (outb) {
        int brow = map_row(m, bmb, bbsd, bro);
        ((ushort4*)(outb + (size_t)brow * ldb))[t] =
            make_ushort4(f2b(o0), f2b(o1), f2b(o2), f2b(o3));
    }
}

// ================= fp32 -> bf16 convert (n4 float4 groups)
__global__ void f2b_kernel(const float* __restrict__ in, unsigned short* __restrict__ out, int n4)
{
    int i = blockIdx.x * 256 + threadIdx.x;
    if (i >= n4) return;
    float4 v = ((const float4*)in)[i];
    ((ushort4*)out)[i] = make_ushort4(f2b(v.x), f2b(v.y), f2b(v.z), f2b(v.w));
}

// ================= merged 6-weight fp32 -> bf16 convert (contiguous bf16 output region)
struct W6 { const float* p[6]; };
__global__ void wconv_kernel(W6 w, unsigned short* __restrict__ out)
{
    const int cum[7] = {0, 262144, 524288, 655360, 786432, 1048576, 1310720};
    int i = blockIdx.x * 256 + threadIdx.x;
    if (i >= 1310720) return;
    int seg = 0;
    #pragma unroll
    for (int s = 1; s < 6; s++) seg += (i >= cum[s]);
    float4 v = ((const float4*)w.p[seg])[i - cum[seg]];
    ((ushort4*)out)[i] = make_ushort4(f2b(v.x), f2b(v.y), f2b(v.z), f2b(v.w));
}

// ================= memory(fp32) -> catb(bf16) rows [b*1536 + 0..1023]
__global__ void mem2catb_kernel(const float* __restrict__ mem, unsigned short* __restrict__ catb)
{
    int f = blockIdx.x * blockDim.x + threadIdx.x;
    const int total = BB * TTM * DM / 4;
    if (f >= total) return;
    const int per_b = TTM * DM / 4;
    int b = f / per_b, rem = f - b * per_b;
    float4 v = ((const float4*)mem)[f];
    ((ushort4*)catb)[(size_t)b * (LCAT * DM / 4) + rem] =
        make_ushort4(f2b(v.x), f2b(v.y), f2b(v.z), f2b(v.w));
}

static void run_scan(const unsigned short* dltb, const unsigned short* xcb, const float* bc,
                     const unsigned short* xzb, const float* A_log, const float* Dv,
                     float* part_h, float* part_s, unsigned short* out, int L,
                     hipStream_t stream)
{
    int CH = L / NC;
    int blocks = BB * NC * (DI / 256);
    scan_part1<<<blocks, 256, 0, stream>>>(dltb, xcb, bc, A_log, part_h, part_s, L, CH);
    scan_combine<<<BB * DI / 256, 256, 0, stream>>>(A_log, part_h, part_s);
    scan_part2<<<blocks, 256, 0, stream>>>(dltb, xcb, bc, xzb, A_log, Dv, part_h, out, L, CH);
}

extern "C" void kernel_launch(void* const* d_in, const int* in_sizes, int n_in,
                              void* d_out, int out_size, void* d_ws, size_t ws_size,
                              hipStream_t stream)
{
    const float* tgt       = (const float*)d_in[0];
    const float* memory    = (const float*)d_in[1];
    const float* s_in_w    = (const float*)d_in[2];
    const float* s_conv_w  = (const float*)d_in[3];
    const float* s_conv_b  = (const float*)d_in[4];
    const float* s_xproj_w = (const float*)d_in[5];
    const float* s_dt_w    = (const float*)d_in[6];
    const float* s_dt_b    = (const float*)d_in[7];
    const float* s_A_log   = (const float*)d_in[8];
    const float* s_D_vec   = (const float*)d_in[9];
    const float* s_out_w   = (const float*)d_in[10];
    const float* c_in_w    = (const float*)d_in[11];
    const float* c_conv_w  = (const float*)d_in[12];
    const float* c_conv_b  = (const float*)d_in[13];
    const float* c_xproj_w = (const float*)d_in[14];
    const float* c_dt_w    = (const float*)d_in[15];
    const float* c_dt_b    = (const float*)d_in[16];
    const float* c_A_log   = (const float*)d_in[17];
    const float* c_D_vec   = (const float*)d_in[18];
    const float* c_out_w   = (const float*)d_in[19];
    const float* ln1_g     = (const float*)d_in[20];
    const float* ln1_b     = (const float*)d_in[21];
    const float* ln2_g     = (const float*)d_in[22];
    const float* ln2_b     = (const float*)d_in[23];
    const float* ln3_g     = (const float*)d_in[24];
    const float* ln3_b     = (const float*)d_in[25];
    const float* ffn_w1    = (const float*)d_in[26];
    const float* ffn_b1    = (const float*)d_in[27];
    const float* ffn_w2    = (const float*)d_in[28];
    const float* ffn_b2    = (const float*)d_in[29];
    float* outp = (float*)d_out;

    // ---- workspace layout ----
    // fp32 region (floats): 11,141,120 floats = 44.6 MB
    float* ws     = (float*)d_ws;
    float* bc     = ws;                     // 393216  (12288 x 32: B|C)
    float* proj   = bc     + 393216;        // 2097152
    float* t1     = proj   + 2097152;       // 2097152
    float* tbuf   = t1     + 2097152;       // 2097152
    float* part_h = tbuf   + 2097152;       // 4194304
    float* part_s = part_h + 4194304;       // 262144
    // bf16 region (ushorts): 81,002,496 elems = 162 MB ; total ~207 MB
    unsigned short* ub      = (unsigned short*)(part_s + 262144);
    unsigned short* dltb    = ub;                   // 12582912 (bf16 delta; ffnout aliases)
    unsigned short* catb    = dltb    + 12582912;   // 6291456
    unsigned short* tgtb    = catb    + 6291456;    // 2097152
    unsigned short* xzb     = tgtb    + 2097152;    // 25165824 (also fbuf alias)
    unsigned short* xcb     = xzb     + 25165824;   // 12582912
    unsigned short* ygb     = xcb     + 12582912;   // 12582912
    unsigned short* tbbf    = ygb     + 12582912;   // 2097152
    unsigned short* s_in_wb = tbbf    + 2097152;    // 1048576  (6-weight block, contiguous)
    unsigned short* c_in_wb = s_in_wb + 1048576;    // 1048576
    unsigned short* s_out_wb= c_in_wb + 1048576;    // 524288
    unsigned short* c_out_wb= s_out_wb+ 524288;     // 524288
    unsigned short* w1b     = c_out_wb+ 524288;     // 1048576
    unsigned short* w2b     = w1b     + 1048576;    // 1048576
    unsigned short* wcomb_s = w2b     + 1048576;    // 1179648 (1152 x 1024)
    unsigned short* wcomb_c = wcomb_s + 1179648;    // 1179648
    unsigned short* fbuf    = xzb;                  // FFN hidden alias
    float* ffnout = (float*)dltb;                   // alias (dltb dead after cross scan)

    // ---- converts & combined-weight fills ----
    f2b_kernel<<<(2097152/4 + 255)/256, 256, 0, stream>>>(tgt, tgtb, 2097152/4);
    mem2catb_kernel<<<(BB*TTM*DM/4 + 255)/256, 256, 0, stream>>>(memory, catb);
    {
        W6 w; w.p[0]=s_in_w; w.p[1]=c_in_w; w.p[2]=s_out_w; w.p[3]=c_out_w; w.p[4]=ffn_w1; w.p[5]=ffn_w2;
        wconv_kernel<<<(1310720 + 255)/256, 256, 0, stream>>>(w, s_in_wb);
    }
    wcomb_kernel<<<(1152*1024)/256, 256, 0, stream>>>(s_dt_w, s_xproj_w, wcomb_s);
    wcomb_kernel<<<(1152*1024)/256, 256, 0, stream>>>(c_dt_w, c_xproj_w, wcomb_c);

    // ---- self mamba (L=512, M=4096) ----
    mgemm_kernel<<<dim3(2048/128, 4096/128), 256, 0, stream>>>(
        tgtb, 4096, 0, 0, s_in_wb, nullptr, nullptr, xzb, nullptr, 2048, 512, ACT_NONE);
    conv_silu_kernel<<<(BB*SS*DI + 255)/256, 256, 0, stream>>>(xzb, s_conv_w, s_conv_b, xcb, SS, BB*SS*DI);
    // combined delta + BC GEMM: M=4096, Ncomb=1152, K=1024
    mgemm_kernel<<<dim3(1152/128, 4096/128), 256, 0, stream>>>(
        xcb, 4096, 0, 0, wcomb_s, s_dt_b, nullptr, dltb, bc, 1152, 1024, ACT_DELTA);
    run_scan(dltb, xcb, bc, xzb, s_A_log, s_D_vec, part_h, part_s, ygb, SS, stream);
    mgemm_kernel<<<dim3(512/128, 4096/128), 256, 0, stream>>>(
        ygb, 4096, 0, 0, s_out_wb, nullptr, proj, nullptr, nullptr, 512, 1024, ACT_NONE);
    // t = LN(tgt + proj): fp32 -> t1, bf16 -> catb rows [b*1536+1024+l]
    addln_kernel<<<4096, 128, 0, stream>>>(
        tgt, 4096, 0, 0, DM, proj, ln1_g, ln1_b,
        t1, 4096, 0, 0, DM, catb, 512, 1536, 1024, DM);

    // ---- cross mamba (L=1536, M=12288) ----
    mgemm_kernel<<<dim3(2048/128, 12288/128), 256, 0, stream>>>(
        catb, 12288, 0, 0, c_in_wb, nullptr, nullptr, xzb, nullptr, 2048, 512, ACT_NONE);
    conv_silu_kernel<<<(BB*LCAT*DI + 255)/256, 256, 0, stream>>>(xzb, c_conv_w, c_conv_b, xcb, LCAT, BB*LCAT*DI);
    mgemm_kernel<<<dim3(1152/128, 12288/128), 256, 0, stream>>>(
        xcb, 12288, 0, 0, wcomb_c, c_dt_b, nullptr, dltb, bc, 1152, 1024, ACT_DELTA);
    run_scan(dltb, xcb, bc, xzb, c_A_log, c_D_vec, part_h, part_s, ygb, LCAT, stream);
    // out proj over last S rows per batch: row(m) = (m/512)*1536 + 1024 + m%512
    mgemm_kernel<<<dim3(512/128, 4096/128), 256, 0, stream>>>(
        ygb, 512, 1536, 1024, c_out_wb, nullptr, proj, nullptr, nullptr, 512, 1024, ACT_NONE);
    addln_kernel<<<4096, 128, 0, stream>>>(
        t1, 4096, 0, 0, DM, proj, ln2_g, ln2_b,
        tbuf, 4096, 0, 0, DM, tbbf, 4096, 0, 0, DM);

    // ---- FFN ----
    mgemm_kernel<<<dim3(2048/128, 4096/128), 256, 0, stream>>>(
        tbbf, 4096, 0, 0, w1b, ffn_b1, nullptr, fbuf, nullptr, 2048, 512, ACT_RELU);
    mgemm_kernel<<<dim3(512/128, 4096/128), 256, 0, stream>>>(
        fbuf, 4096, 0, 0, w2b, ffn_b2, ffnout, nullptr, nullptr, 512, 2048, ACT_NONE);
    addln_kernel<<<4096, 128, 0, stream>>>(
        tbuf, 4096, 0, 0, DM, ffnout, ln3_g, ln3_b,
        outp, 4096, 0, 0, DM, nullptr, 0, 0, 0, 0);
}